// Round 4
// baseline (757.651 us; speedup 1.0000x reference)
//
#include <hip/hip_runtime.h>
#include <hip/hip_bf16.h>
#include <math.h>

#define N_NODES 10000
#define E_EDGES 320000
#define F_IN    384
#define H1      256
#define H2      128
#define ATT1    64
#define DSTRIDE 128   // fixed CSR stride; P(deg>=128) ~ 4e-32 for Binomial(320k, 1e-4)

#define NBLK    1024  // 4 blocks/CU x 256 CUs; co-residency guaranteed by launch_bounds
#define NTHR    256

typedef __attribute__((ext_vector_type(8))) short bf16x8;
typedef __attribute__((ext_vector_type(4))) float f32x4;

static __device__ inline unsigned short f2bf(float f) {
    unsigned u = __float_as_uint(f);
    unsigned r = (u + 0x7fffu + ((u >> 16) & 1u)) >> 16;   // RNE
    return (unsigned short)r;
}

static __device__ inline unsigned pk2bf(float a, float b) {
    __hip_bfloat162 h2 = __float22bfloat162_rn(make_float2(a, b));
    return *reinterpret_cast<unsigned*>(&h2);   // v_cvt_pk_bf16_f32
}

static __device__ inline float bflo(unsigned v) { return __uint_as_float(v << 16); }
static __device__ inline float bfhi(unsigned v) { return __uint_as_float(v & 0xffff0000u); }
static __device__ inline float bf2f(short s) {
    return __uint_as_float(((unsigned)(unsigned short)s) << 16);
}

// device-scope grid barrier: slot = {cnt @ +0, gate @ +16}, 128B-padded, pre-zeroed
// by hipMemsetAsync each launch. Bounded spin: a residency/visibility failure
// terminates with wrong results (diagnosable) instead of hanging the container.
static __device__ inline void gridbar(int* bar, int slot) {
    __threadfence();            // release: make this thread's writes device-visible
    __syncthreads();            // all threads of block have fenced
    if (threadIdx.x == 0) {
        int* cnt  = bar + slot * 32;
        int* gate = bar + slot * 32 + 16;
        if (__hip_atomic_fetch_add(cnt, 1, __ATOMIC_ACQ_REL, __HIP_MEMORY_SCOPE_AGENT)
            == NBLK - 1) {
            __hip_atomic_store(gate, 1, __ATOMIC_RELEASE, __HIP_MEMORY_SCOPE_AGENT);
        } else {
            int spins = 0;
            while (__hip_atomic_load(gate, __ATOMIC_ACQUIRE, __HIP_MEMORY_SCOPE_AGENT) == 0) {
                __builtin_amdgcn_s_sleep(2);
                if (++spins > (1 << 24)) break;   // failsafe ~0.1s >> any real phase
            }
        }
    }
    __syncthreads();
    __threadfence();            // acquire side: invalidate stale cached lines
}

// phase-0 item counts (weight repacks + cursor zeroing)
#define NW1 (H1 * F_IN / 8)   // 12288 uint4 slots
#define NW2 (H2 * H1 / 8)     // 4096
#define NWA (ATT1 * H2 / 4)   // 2048 float4s
#define NCZ (N_NODES / 4)     // 2500 int4 zeroes
#define NPH0 (NW1 + NW2 + NWA + NCZ)   // 20932

#define NBLK_FC 625   // M=16 GEMM tiles (exact: 10000/16)
#define XS 392        // LDS row stride (ushorts) for the 16x384 x tile
#define S1 264        // LDS row stride (ushorts) for the 16x256 h tile

#define ACC8(v) { s0 += bflo(v.x); s1 += bfhi(v.x); s2 += bflo(v.y); s3 += bfhi(v.y); \
                  s4 += bflo(v.z); s5 += bfhi(v.z); s6 += bflo(v.w); s7 += bfhi(v.w); }

__global__ __launch_bounds__(NTHR, 4) void k_fused(
    const float* __restrict__ x, const int* __restrict__ srcv, const int* __restrict__ tgt,
    const float* __restrict__ W1, const float* __restrict__ b1,
    const float* __restrict__ W2, const float* __restrict__ b2,
    const float* __restrict__ Wa1, const float* __restrict__ ba1,
    const float* __restrict__ Wa2, const float* __restrict__ ba2,
    unsigned short* __restrict__ w1b, unsigned short* __restrict__ w2b,
    unsigned short* __restrict__ wa1b,
    unsigned short* __restrict__ z0, unsigned short* __restrict__ z1,
    int* __restrict__ cursor, int* __restrict__ csrf, int* bar,
    float* __restrict__ out, float* __restrict__ att) {

    __shared__ unsigned short smem[16 * XS];   // 12.5 KB GEMM tile (x, then h)
    __shared__ float sout[4][128];             // 2 KB att staging

    const int bid = blockIdx.x;
    const int tid = threadIdx.x;

    // ---------------- phase 0: weight repacks (frag-linear) + cursor zeroing
    {
        int i = bid * NTHR + tid;
        if (i < NW1) {
            int s = i;
            int jb = s / 768, rem = s - jb * 768;
            int kk = rem >> 6, lane = rem & 63;
            int ml = lane & 15, quad = lane >> 4;
            const float* p = W1 + (size_t)(jb * 16 + ml) * F_IN + kk * 32 + quad * 8;
            float4 u0 = *(const float4*)p;
            float4 u1 = *(const float4*)(p + 4);
            uint4 o;
            o.x = pk2bf(u0.x, u0.y); o.y = pk2bf(u0.z, u0.w);
            o.z = pk2bf(u1.x, u1.y); o.w = pk2bf(u1.z, u1.w);
            ((uint4*)w1b)[s] = o;
        } else if (i < NW1 + NW2) {
            int s = i - NW1;
            int jcol = s / 512, rem = s - jcol * 512;
            int kk = rem >> 6, lane = rem & 63;
            int ml = lane & 15, quad = lane >> 4;
            const float* p = W2 + (size_t)(jcol * 16 + ml) * H1 + kk * 32 + quad * 8;
            float4 u0 = *(const float4*)p;
            float4 u1 = *(const float4*)(p + 4);
            uint4 o;
            o.x = pk2bf(u0.x, u0.y); o.y = pk2bf(u0.z, u0.w);
            o.z = pk2bf(u1.x, u1.y); o.w = pk2bf(u1.z, u1.w);
            ((uint4*)w2b)[s] = o;
        } else if (i < NW1 + NW2 + NWA) {
            int j = i - NW1 - NW2;
            float4 v = ((const float4*)Wa1)[j];
            ushort4 o;
            o.x = f2bf(v.x); o.y = f2bf(v.y); o.z = f2bf(v.z); o.w = f2bf(v.w);
            ((ushort4*)wa1b)[j] = o;
        } else if (i < NPH0) {
            int j = i - NW1 - NW2 - NWA;
            ((int4*)cursor)[j] = make_int4(0, 0, 0, 0);
        }
    }
    gridbar(bar, 0);

    // ---------------- phase 1: fc1+proj GEMM (blocks 0..624) || CSR fill (625..1023)
    if (bid < NBLK_FC) {
        int wave = tid >> 6;
        int lane = tid & 63;
        int m0 = bid * 16;
        int ml = lane & 15, quad = lane >> 4;
        {   // stage x tile: 16 rows x 384 fp32 (24 KB contiguous) -> bf16 LDS
            const float4* xsrc = (const float4*)(x + (size_t)m0 * F_IN);
            #pragma unroll
            for (int r = 0; r < 6; r++) {
                int idx = r * 256 + tid;
                float4 v = xsrc[idx];
                int row = idx / 96, c4 = idx - row * 96;
                unsigned* sp = (unsigned*)(smem + row * XS + c4 * 4);
                sp[0] = pk2bf(v.x, v.y);
                sp[1] = pk2bf(v.z, v.w);
            }
        }
        __syncthreads();
        f32x4 acc[4] = {{0,0,0,0},{0,0,0,0},{0,0,0,0},{0,0,0,0}};
        {   // stage 1 K-loop: A from LDS, B frag-linear coalesced
            const unsigned short* ax = smem + ml * XS + quad * 8;
            const bf16x8* W1f = (const bf16x8*)w1b;
            for (int kk = 0; kk < F_IN / 32; kk++) {
                bf16x8 a = *(const bf16x8*)(ax + kk * 32);
                #pragma unroll
                for (int j = 0; j < 4; j++) {
                    int jb = wave * 4 + j;
                    bf16x8 b = W1f[(jb * 12 + kk) * 64 + lane];
                    acc[j] = __builtin_amdgcn_mfma_f32_16x16x32_bf16(a, b, acc[j], 0, 0, 0);
                }
            }
        }
        __syncthreads();
        #pragma unroll
        for (int j = 0; j < 4; j++) {
            int col = wave * 64 + j * 16 + ml;
            float bb = b1[col];
            #pragma unroll
            for (int r = 0; r < 4; r++) {
                int lr = quad * 4 + r;
                float v = acc[j][r] + bb;
                smem[lr * S1 + col] = f2bf(v > 0.f ? v : 0.f);
            }
        }
        __syncthreads();
        {   // stage 2: z0 = h @ W2^T
            int c0 = wave * 32;
            const unsigned short* pA = smem + ml * S1 + quad * 8;
            const bf16x8* W2f = (const bf16x8*)w2b;
            f32x4 za0 = {0,0,0,0}, za1 = {0,0,0,0};
            #pragma unroll
            for (int kk = 0; kk < H1 / 32; kk++) {
                bf16x8 a = *(const bf16x8*)(pA + kk * 32);
                bf16x8 b0 = W2f[((wave * 2 + 0) * 8 + kk) * 64 + lane];
                bf16x8 b1v = W2f[((wave * 2 + 1) * 8 + kk) * 64 + lane];
                za0 = __builtin_amdgcn_mfma_f32_16x16x32_bf16(a, b0, za0, 0, 0, 0);
                za1 = __builtin_amdgcn_mfma_f32_16x16x32_bf16(a, b1v, za1, 0, 0, 0);
            }
            #pragma unroll
            for (int r = 0; r < 4; r++) {
                int row = m0 + quad * 4 + r;
                z0[(size_t)row * H2 + c0 + ml] = f2bf(za0[r]);
                z0[(size_t)row * H2 + c0 + 16 + ml] = f2bf(za1[r]);
            }
        }
    } else {
        // CSR fill: 399 blocks, grid-stride over edges (plain stores: keep csrf in L2)
        for (int e = (bid - NBLK_FC) * NTHR + tid; e < E_EDGES; e += (NBLK - NBLK_FC) * NTHR) {
            int t = tgt[e];
            int p = atomicAdd(&cursor[t], 1);
            if (p < DSTRIDE) csrf[t * DSTRIDE + p] = srcv[e];
        }
    }
    gridbar(bar, 1);

    // ---------------- phase 2: agg pass 1 (z0 -> z1)
    {
        int lane = tid & 63;
        int l = lane & 15, quad = lane >> 4;
        const uint4* base = (const uint4*)z0;
        for (int g = bid; g < N_NODES / 4; g += NBLK) {
            int t = g * 4 + (tid >> 6);
            int dg = cursor[t];
            if (dg > DSTRIDE) dg = DSTRIDE;
            uint4 sv = make_uint4(0, 0, 0, 0);
            if (quad == 0) sv = base[(size_t)t * 16 + l];
            float s0=0.f,s1=0.f,s2=0.f,s3=0.f,s4=0.f,s5=0.f,s6=0.f,s7=0.f;
            for (int e0 = 0; e0 < dg; e0 += 64) {
                int cnt = dg - e0; if (cnt > 64) cnt = 64;
                int c = (e0 + lane < dg) ? csrf[t * DSTRIDE + e0 + lane] : 0;
                for (int j = 0; j < cnt; j += 16) {
                    int sA = __shfl(c, j + quad, 64);
                    int sB = __shfl(c, j + 4 + quad, 64);
                    int sC = __shfl(c, j + 8 + quad, 64);
                    int sD = __shfl(c, j + 12 + quad, 64);
                    uint4 vA = base[(size_t)sA * 16 + l];
                    uint4 vB = base[(size_t)sB * 16 + l];
                    uint4 vC = base[(size_t)sC * 16 + l];
                    uint4 vD = base[(size_t)sD * 16 + l];
                    if (j + quad < cnt)      ACC8(vA);
                    if (j + 4 + quad < cnt)  ACC8(vB);
                    if (j + 8 + quad < cnt)  ACC8(vC);
                    if (j + 12 + quad < cnt) ACC8(vD);
                }
            }
            s0 += __shfl_xor(s0, 16, 64); s0 += __shfl_xor(s0, 32, 64);
            s1 += __shfl_xor(s1, 16, 64); s1 += __shfl_xor(s1, 32, 64);
            s2 += __shfl_xor(s2, 16, 64); s2 += __shfl_xor(s2, 32, 64);
            s3 += __shfl_xor(s3, 16, 64); s3 += __shfl_xor(s3, 32, 64);
            s4 += __shfl_xor(s4, 16, 64); s4 += __shfl_xor(s4, 32, 64);
            s5 += __shfl_xor(s5, 16, 64); s5 += __shfl_xor(s5, 32, 64);
            s6 += __shfl_xor(s6, 16, 64); s6 += __shfl_xor(s6, 32, 64);
            s7 += __shfl_xor(s7, 16, 64); s7 += __shfl_xor(s7, 32, 64);
            if (quad == 0) {
                float iv = 0.3f / (float)(dg + 1);
                uint4 o;
                o.x = pk2bf(0.7f * bflo(sv.x) + iv * s0, 0.7f * bfhi(sv.x) + iv * s1);
                o.y = pk2bf(0.7f * bflo(sv.y) + iv * s2, 0.7f * bfhi(sv.y) + iv * s3);
                o.z = pk2bf(0.7f * bflo(sv.z) + iv * s4, 0.7f * bfhi(sv.z) + iv * s5);
                o.w = pk2bf(0.7f * bflo(sv.w) + iv * s6, 0.7f * bfhi(sv.w) + iv * s7);
                ((uint4*)z1)[(size_t)t * 16 + l] = o;
            }
        }
    }
    gridbar(bar, 2);

    // ---------------- phase 3: agg pass 2 + bias/relu -> out, att head -> att
    {
        int nl = tid >> 6;
        int lane = tid & 63;
        int l = lane & 15, quad = lane >> 4;
        const uint4* base = (const uint4*)z1;
        for (int g = bid; g < N_NODES / 4; g += NBLK) {
            int t = g * 4 + nl;
            int dg = cursor[t];
            if (dg > DSTRIDE) dg = DSTRIDE;
            uint4 sv = base[(size_t)t * 16 + l];
            float s0=0.f,s1=0.f,s2=0.f,s3=0.f,s4=0.f,s5=0.f,s6=0.f,s7=0.f;
            for (int e0 = 0; e0 < dg; e0 += 64) {
                int cnt = dg - e0; if (cnt > 64) cnt = 64;
                int c = (e0 + lane < dg) ? csrf[t * DSTRIDE + e0 + lane] : 0;
                for (int j = 0; j < cnt; j += 16) {
                    int sA = __shfl(c, j + quad, 64);
                    int sB = __shfl(c, j + 4 + quad, 64);
                    int sC = __shfl(c, j + 8 + quad, 64);
                    int sD = __shfl(c, j + 12 + quad, 64);
                    uint4 vA = base[(size_t)sA * 16 + l];
                    uint4 vB = base[(size_t)sB * 16 + l];
                    uint4 vC = base[(size_t)sC * 16 + l];
                    uint4 vD = base[(size_t)sD * 16 + l];
                    if (j + quad < cnt)      ACC8(vA);
                    if (j + 4 + quad < cnt)  ACC8(vB);
                    if (j + 8 + quad < cnt)  ACC8(vC);
                    if (j + 12 + quad < cnt) ACC8(vD);
                }
            }
            s0 += __shfl_xor(s0, 16, 64); s0 += __shfl_xor(s0, 32, 64);
            s1 += __shfl_xor(s1, 16, 64); s1 += __shfl_xor(s1, 32, 64);
            s2 += __shfl_xor(s2, 16, 64); s2 += __shfl_xor(s2, 32, 64);
            s3 += __shfl_xor(s3, 16, 64); s3 += __shfl_xor(s3, 32, 64);
            s4 += __shfl_xor(s4, 16, 64); s4 += __shfl_xor(s4, 32, 64);
            s5 += __shfl_xor(s5, 16, 64); s5 += __shfl_xor(s5, 32, 64);
            s6 += __shfl_xor(s6, 16, 64); s6 += __shfl_xor(s6, 32, 64);
            s7 += __shfl_xor(s7, 16, 64); s7 += __shfl_xor(s7, 32, 64);
            float iv = 0.3f / (float)(dg + 1);
            const float4* bp = (const float4*)(b2 + l * 8);
            float4 bA = bp[0], bB = bp[1];
            float f0 = 0.7f * bflo(sv.x) + iv * s0 + bA.x;  f0 = f0 > 0.f ? f0 : 0.f;
            float f1 = 0.7f * bfhi(sv.x) + iv * s1 + bA.y;  f1 = f1 > 0.f ? f1 : 0.f;
            float f2 = 0.7f * bflo(sv.y) + iv * s2 + bA.z;  f2 = f2 > 0.f ? f2 : 0.f;
            float f3 = 0.7f * bfhi(sv.y) + iv * s3 + bA.w;  f3 = f3 > 0.f ? f3 : 0.f;
            float f4 = 0.7f * bflo(sv.z) + iv * s4 + bB.x;  f4 = f4 > 0.f ? f4 : 0.f;
            float f5 = 0.7f * bfhi(sv.z) + iv * s5 + bB.y;  f5 = f5 > 0.f ? f5 : 0.f;
            float f6 = 0.7f * bflo(sv.w) + iv * s6 + bB.z;  f6 = f6 > 0.f ? f6 : 0.f;
            float f7 = 0.7f * bfhi(sv.w) + iv * s7 + bB.w;  f7 = f7 > 0.f ? f7 : 0.f;
            float* orow = out + (size_t)t * H2 + l * 8;
            if (quad == 0) *(float4*)orow = make_float4(f0, f1, f2, f3);
            else if (quad == 1) *(float4*)(orow + 4) = make_float4(f4, f5, f6, f7);
            else if (quad == 2) *(float4*)(&sout[nl][l * 8]) = make_float4(f0, f1, f2, f3);
            else *(float4*)(&sout[nl][l * 8 + 4]) = make_float4(f4, f5, f6, f7);
            // att: lane u computes hidden unit u: dot(out_row, Wa1[u]) over K=128
            float acc = ba1[lane];
            const bf16x8* wrow = (const bf16x8*)(wa1b + (size_t)lane * H2);
            const float* srow = sout[nl];
            #pragma unroll
            for (int k8 = 0; k8 < 16; k8++) {
                bf16x8 w = wrow[k8];
                #pragma unroll
                for (int u = 0; u < 8; u++)
                    acc += bf2f(w[u]) * srow[k8 * 8 + u];
            }
            float gg = (acc > 0.f ? acc : 0.f) * Wa2[lane];
            #pragma unroll
            for (int d = 1; d < 64; d <<= 1) gg += __shfl_xor(gg, d, 64);
            if (lane == 0) att[t] = 1.f / (1.f + expf(-gg));
        }
    }
}

extern "C" void kernel_launch(void* const* d_in, const int* in_sizes, int n_in,
                              void* d_out, int out_size, void* d_ws, size_t ws_size,
                              hipStream_t stream) {
    const float* x   = (const float*)d_in[0];
    const int*   ei  = (const int*)d_in[1];
    const float* W1  = (const float*)d_in[2];
    const float* b1  = (const float*)d_in[3];
    const float* W2  = (const float*)d_in[4];
    const float* b2  = (const float*)d_in[5];
    const float* Wa1 = (const float*)d_in[6];
    const float* ba1 = (const float*)d_in[7];
    const float* Wa2 = (const float*)d_in[8];
    const float* ba2 = (const float*)d_in[9];
    const int* srcv = ei;
    const int* tgt  = ei + E_EDGES;

    float* out_mat = (float*)d_out;                 // N x 128
    float* att     = out_mat + N_NODES * H2;        // N x 1

    // workspace layout
    unsigned short* w1b  = (unsigned short*)d_ws;                // H1*F_IN (frag-linear)
    unsigned short* w2b  = w1b + (size_t)H1 * F_IN;              // H2*H1   (frag-linear)
    unsigned short* wa1b = w2b + (size_t)H2 * H1;                // ATT1*H2 (row-major)
    unsigned short* z0   = wa1b + (size_t)ATT1 * H2;             // N*128
    unsigned short* z1   = z0 + (size_t)N_NODES * H2;            // N*128
    int* cursor = (int*)(z1 + (size_t)N_NODES * H2);             // N
    int* csrf   = cursor + N_NODES;                              // N*DSTRIDE
    int* bar    = csrf + (size_t)N_NODES * DSTRIDE;              // 128 ints (3 slots used)

    hipMemsetAsync(bar, 0, 512, stream);   // barrier slots must be zero each launch

    k_fused<<<NBLK, NTHR, 0, stream>>>(x, srcv, tgt, W1, b1, W2, b2, Wa1, ba1, Wa2, ba2,
                                       w1b, w2b, wa1b, z0, z1, cursor, csrf, bar,
                                       out_mat, att);
}

// Round 5
// 252.691 us; speedup vs baseline: 2.9983x; 2.9983x over previous
//
#include <hip/hip_runtime.h>
#include <hip/hip_bf16.h>
#include <math.h>

#define N_NODES 10000
#define E_EDGES 320000
#define F_IN    384
#define H1      256
#define H2      128
#define ATT1    64
#define DSTRIDE 128   // fixed CSR stride; P(deg>=128) ~ 4e-32 for Binomial(320k, 1e-4)

#define NBLK    1024  // 4 blocks/CU x 256 CUs; co-residency guaranteed by launch_bounds
#define NTHR    256

typedef __attribute__((ext_vector_type(8))) short bf16x8;
typedef __attribute__((ext_vector_type(4))) float f32x4;

static __device__ inline unsigned short f2bf(float f) {
    unsigned u = __float_as_uint(f);
    unsigned r = (u + 0x7fffu + ((u >> 16) & 1u)) >> 16;   // RNE
    return (unsigned short)r;
}

static __device__ inline unsigned pk2bf(float a, float b) {
    __hip_bfloat162 h2 = __float22bfloat162_rn(make_float2(a, b));
    return *reinterpret_cast<unsigned*>(&h2);   // v_cvt_pk_bf16_f32
}

static __device__ inline float bflo(unsigned v) { return __uint_as_float(v << 16); }
static __device__ inline float bfhi(unsigned v) { return __uint_as_float(v & 0xffff0000u); }
static __device__ inline float bf2f(short s) {
    return __uint_as_float(((unsigned)(unsigned short)s) << 16);
}

// Device-scope grid barrier, fence-storm-free (round-4 post-mortem):
// - RELAXED agent atomics for arrive/spin: executed at the coherence point,
//   NO per-op L2 writeback/invalidate (the ACQUIRE-per-poll in round 4 emitted
//   buffer_inv each ~50ns x 1024 blocks = continuous L2 wipe on all XCDs).
// - Exactly one RELEASE fence (L2 writeback) before arrive and one ACQUIRE
//   fence (L2 invalidate) after the gate flips, per block per barrier.
// - s_sleep(16) ~0.4us poll gap: negligible fabric traffic, ~0.2us detect.
// Bounded spin: failure terminates with wrong results (diagnosable), no hang.
static __device__ inline void gridbar(int* bar, int slot) {
    __syncthreads();
    if (threadIdx.x == 0) {
        int* cnt  = bar + slot * 64;        // slots 256B apart
        int* gate = bar + slot * 64 + 32;   // gate 128B from cnt (separate line)
        __builtin_amdgcn_fence(__ATOMIC_RELEASE, "agent");   // wb dirty L2 once
        if (__hip_atomic_fetch_add(cnt, 1, __ATOMIC_RELAXED, __HIP_MEMORY_SCOPE_AGENT)
            == NBLK - 1) {
            __hip_atomic_store(gate, 1, __ATOMIC_RELAXED, __HIP_MEMORY_SCOPE_AGENT);
        } else {
            int spins = 0;
            while (__hip_atomic_load(gate, __ATOMIC_RELAXED, __HIP_MEMORY_SCOPE_AGENT) == 0) {
                __builtin_amdgcn_s_sleep(16);
                if (++spins > (1 << 20)) break;   // failsafe ~0.4s >> any real phase
            }
        }
        __builtin_amdgcn_fence(__ATOMIC_ACQUIRE, "agent");   // inv stale L2 once
    }
    __syncthreads();
}

// phase-0 item counts (weight repacks + cursor zeroing)
#define NW1 (H1 * F_IN / 8)   // 12288 uint4 slots
#define NW2 (H2 * H1 / 8)     // 4096
#define NWA (ATT1 * H2 / 4)   // 2048 float4s
#define NCZ (N_NODES / 4)     // 2500 int4 zeroes
#define NPH0 (NW1 + NW2 + NWA + NCZ)   // 20932

#define NBLK_FC 625   // M=16 GEMM tiles (exact: 10000/16)
#define XS 392        // LDS row stride (ushorts) for the 16x384 x tile
#define S1 264        // LDS row stride (ushorts) for the 16x256 h tile

#define ACC8(v) { s0 += bflo(v.x); s1 += bfhi(v.x); s2 += bflo(v.y); s3 += bfhi(v.y); \
                  s4 += bflo(v.z); s5 += bfhi(v.z); s6 += bflo(v.w); s7 += bfhi(v.w); }

__global__ __launch_bounds__(NTHR, 4) void k_fused(
    const float* __restrict__ x, const int* __restrict__ srcv, const int* __restrict__ tgt,
    const float* __restrict__ W1, const float* __restrict__ b1,
    const float* __restrict__ W2, const float* __restrict__ b2,
    const float* __restrict__ Wa1, const float* __restrict__ ba1,
    const float* __restrict__ Wa2, const float* __restrict__ ba2,
    unsigned short* __restrict__ w1b, unsigned short* __restrict__ w2b,
    unsigned short* __restrict__ wa1b,
    unsigned short* __restrict__ z0, unsigned short* __restrict__ z1,
    int* __restrict__ cursor, int* __restrict__ csrf, int* bar,
    float* __restrict__ out, float* __restrict__ att) {

    __shared__ unsigned short smem[16 * XS];   // 12.5 KB GEMM tile (x, then h)
    __shared__ float sout[4][128];             // 2 KB att staging

    const int bid = blockIdx.x;
    const int tid = threadIdx.x;

    // ---------------- phase 0: weight repacks (frag-linear) + cursor zeroing
    {
        int i = bid * NTHR + tid;
        if (i < NW1) {
            int s = i;
            int jb = s / 768, rem = s - jb * 768;
            int kk = rem >> 6, lane = rem & 63;
            int ml = lane & 15, quad = lane >> 4;
            const float* p = W1 + (size_t)(jb * 16 + ml) * F_IN + kk * 32 + quad * 8;
            float4 u0 = *(const float4*)p;
            float4 u1 = *(const float4*)(p + 4);
            uint4 o;
            o.x = pk2bf(u0.x, u0.y); o.y = pk2bf(u0.z, u0.w);
            o.z = pk2bf(u1.x, u1.y); o.w = pk2bf(u1.z, u1.w);
            ((uint4*)w1b)[s] = o;
        } else if (i < NW1 + NW2) {
            int s = i - NW1;
            int jcol = s / 512, rem = s - jcol * 512;
            int kk = rem >> 6, lane = rem & 63;
            int ml = lane & 15, quad = lane >> 4;
            const float* p = W2 + (size_t)(jcol * 16 + ml) * H1 + kk * 32 + quad * 8;
            float4 u0 = *(const float4*)p;
            float4 u1 = *(const float4*)(p + 4);
            uint4 o;
            o.x = pk2bf(u0.x, u0.y); o.y = pk2bf(u0.z, u0.w);
            o.z = pk2bf(u1.x, u1.y); o.w = pk2bf(u1.z, u1.w);
            ((uint4*)w2b)[s] = o;
        } else if (i < NW1 + NW2 + NWA) {
            int j = i - NW1 - NW2;
            float4 v = ((const float4*)Wa1)[j];
            ushort4 o;
            o.x = f2bf(v.x); o.y = f2bf(v.y); o.z = f2bf(v.z); o.w = f2bf(v.w);
            ((ushort4*)wa1b)[j] = o;
        } else if (i < NPH0) {
            int j = i - NW1 - NW2 - NWA;
            ((int4*)cursor)[j] = make_int4(0, 0, 0, 0);
        }
    }
    gridbar(bar, 0);

    // ---------------- phase 1: fc1+proj GEMM (blocks 0..624) || CSR fill (625..1023)
    if (bid < NBLK_FC) {
        int wave = tid >> 6;
        int lane = tid & 63;
        int m0 = bid * 16;
        int ml = lane & 15, quad = lane >> 4;
        {   // stage x tile: 16 rows x 384 fp32 (24 KB contiguous) -> bf16 LDS
            const float4* xsrc = (const float4*)(x + (size_t)m0 * F_IN);
            #pragma unroll
            for (int r = 0; r < 6; r++) {
                int idx = r * 256 + tid;
                float4 v = xsrc[idx];
                int row = idx / 96, c4 = idx - row * 96;
                unsigned* sp = (unsigned*)(smem + row * XS + c4 * 4);
                sp[0] = pk2bf(v.x, v.y);
                sp[1] = pk2bf(v.z, v.w);
            }
        }
        __syncthreads();
        f32x4 acc[4] = {{0,0,0,0},{0,0,0,0},{0,0,0,0},{0,0,0,0}};
        {   // stage 1 K-loop: A from LDS, B frag-linear coalesced
            const unsigned short* ax = smem + ml * XS + quad * 8;
            const bf16x8* W1f = (const bf16x8*)w1b;
            for (int kk = 0; kk < F_IN / 32; kk++) {
                bf16x8 a = *(const bf16x8*)(ax + kk * 32);
                #pragma unroll
                for (int j = 0; j < 4; j++) {
                    int jb = wave * 4 + j;
                    bf16x8 b = W1f[(jb * 12 + kk) * 64 + lane];
                    acc[j] = __builtin_amdgcn_mfma_f32_16x16x32_bf16(a, b, acc[j], 0, 0, 0);
                }
            }
        }
        __syncthreads();
        #pragma unroll
        for (int j = 0; j < 4; j++) {
            int col = wave * 64 + j * 16 + ml;
            float bb = b1[col];
            #pragma unroll
            for (int r = 0; r < 4; r++) {
                int lr = quad * 4 + r;
                float v = acc[j][r] + bb;
                smem[lr * S1 + col] = f2bf(v > 0.f ? v : 0.f);
            }
        }
        __syncthreads();
        {   // stage 2: z0 = h @ W2^T
            int c0 = wave * 32;
            const unsigned short* pA = smem + ml * S1 + quad * 8;
            const bf16x8* W2f = (const bf16x8*)w2b;
            f32x4 za0 = {0,0,0,0}, za1 = {0,0,0,0};
            #pragma unroll
            for (int kk = 0; kk < H1 / 32; kk++) {
                bf16x8 a = *(const bf16x8*)(pA + kk * 32);
                bf16x8 b0 = W2f[((wave * 2 + 0) * 8 + kk) * 64 + lane];
                bf16x8 b1v = W2f[((wave * 2 + 1) * 8 + kk) * 64 + lane];
                za0 = __builtin_amdgcn_mfma_f32_16x16x32_bf16(a, b0, za0, 0, 0, 0);
                za1 = __builtin_amdgcn_mfma_f32_16x16x32_bf16(a, b1v, za1, 0, 0, 0);
            }
            #pragma unroll
            for (int r = 0; r < 4; r++) {
                int row = m0 + quad * 4 + r;
                z0[(size_t)row * H2 + c0 + ml] = f2bf(za0[r]);
                z0[(size_t)row * H2 + c0 + 16 + ml] = f2bf(za1[r]);
            }
        }
    } else {
        // CSR fill: 399 blocks, grid-stride over edges (plain stores: keep csrf cached)
        for (int e = (bid - NBLK_FC) * NTHR + tid; e < E_EDGES; e += (NBLK - NBLK_FC) * NTHR) {
            int t = tgt[e];
            int p = atomicAdd(&cursor[t], 1);
            if (p < DSTRIDE) csrf[t * DSTRIDE + p] = srcv[e];
        }
    }
    gridbar(bar, 1);

    // ---------------- phase 2: agg pass 1 (z0 -> z1)
    {
        int lane = tid & 63;
        int l = lane & 15, quad = lane >> 4;
        const uint4* base = (const uint4*)z0;
        for (int g = bid; g < N_NODES / 4; g += NBLK) {
            int t = g * 4 + (tid >> 6);
            int dg = cursor[t];
            if (dg > DSTRIDE) dg = DSTRIDE;
            uint4 sv = make_uint4(0, 0, 0, 0);
            if (quad == 0) sv = base[(size_t)t * 16 + l];
            float s0=0.f,s1=0.f,s2=0.f,s3=0.f,s4=0.f,s5=0.f,s6=0.f,s7=0.f;
            for (int e0 = 0; e0 < dg; e0 += 64) {
                int cnt = dg - e0; if (cnt > 64) cnt = 64;
                int c = (e0 + lane < dg) ? csrf[t * DSTRIDE + e0 + lane] : 0;
                for (int j = 0; j < cnt; j += 16) {
                    int sA = __shfl(c, j + quad, 64);
                    int sB = __shfl(c, j + 4 + quad, 64);
                    int sC = __shfl(c, j + 8 + quad, 64);
                    int sD = __shfl(c, j + 12 + quad, 64);
                    uint4 vA = base[(size_t)sA * 16 + l];
                    uint4 vB = base[(size_t)sB * 16 + l];
                    uint4 vC = base[(size_t)sC * 16 + l];
                    uint4 vD = base[(size_t)sD * 16 + l];
                    if (j + quad < cnt)      ACC8(vA);
                    if (j + 4 + quad < cnt)  ACC8(vB);
                    if (j + 8 + quad < cnt)  ACC8(vC);
                    if (j + 12 + quad < cnt) ACC8(vD);
                }
            }
            s0 += __shfl_xor(s0, 16, 64); s0 += __shfl_xor(s0, 32, 64);
            s1 += __shfl_xor(s1, 16, 64); s1 += __shfl_xor(s1, 32, 64);
            s2 += __shfl_xor(s2, 16, 64); s2 += __shfl_xor(s2, 32, 64);
            s3 += __shfl_xor(s3, 16, 64); s3 += __shfl_xor(s3, 32, 64);
            s4 += __shfl_xor(s4, 16, 64); s4 += __shfl_xor(s4, 32, 64);
            s5 += __shfl_xor(s5, 16, 64); s5 += __shfl_xor(s5, 32, 64);
            s6 += __shfl_xor(s6, 16, 64); s6 += __shfl_xor(s6, 32, 64);
            s7 += __shfl_xor(s7, 16, 64); s7 += __shfl_xor(s7, 32, 64);
            if (quad == 0) {
                float iv = 0.3f / (float)(dg + 1);
                uint4 o;
                o.x = pk2bf(0.7f * bflo(sv.x) + iv * s0, 0.7f * bfhi(sv.x) + iv * s1);
                o.y = pk2bf(0.7f * bflo(sv.y) + iv * s2, 0.7f * bfhi(sv.y) + iv * s3);
                o.z = pk2bf(0.7f * bflo(sv.z) + iv * s4, 0.7f * bfhi(sv.z) + iv * s5);
                o.w = pk2bf(0.7f * bflo(sv.w) + iv * s6, 0.7f * bfhi(sv.w) + iv * s7);
                ((uint4*)z1)[(size_t)t * 16 + l] = o;
            }
        }
    }
    gridbar(bar, 2);

    // ---------------- phase 3: agg pass 2 + bias/relu -> out, att head -> att
    {
        int nl = tid >> 6;
        int lane = tid & 63;
        int l = lane & 15, quad = lane >> 4;
        const uint4* base = (const uint4*)z1;
        for (int g = bid; g < N_NODES / 4; g += NBLK) {
            int t = g * 4 + nl;
            int dg = cursor[t];
            if (dg > DSTRIDE) dg = DSTRIDE;
            uint4 sv = base[(size_t)t * 16 + l];
            float s0=0.f,s1=0.f,s2=0.f,s3=0.f,s4=0.f,s5=0.f,s6=0.f,s7=0.f;
            for (int e0 = 0; e0 < dg; e0 += 64) {
                int cnt = dg - e0; if (cnt > 64) cnt = 64;
                int c = (e0 + lane < dg) ? csrf[t * DSTRIDE + e0 + lane] : 0;
                for (int j = 0; j < cnt; j += 16) {
                    int sA = __shfl(c, j + quad, 64);
                    int sB = __shfl(c, j + 4 + quad, 64);
                    int sC = __shfl(c, j + 8 + quad, 64);
                    int sD = __shfl(c, j + 12 + quad, 64);
                    uint4 vA = base[(size_t)sA * 16 + l];
                    uint4 vB = base[(size_t)sB * 16 + l];
                    uint4 vC = base[(size_t)sC * 16 + l];
                    uint4 vD = base[(size_t)sD * 16 + l];
                    if (j + quad < cnt)      ACC8(vA);
                    if (j + 4 + quad < cnt)  ACC8(vB);
                    if (j + 8 + quad < cnt)  ACC8(vC);
                    if (j + 12 + quad < cnt) ACC8(vD);
                }
            }
            s0 += __shfl_xor(s0, 16, 64); s0 += __shfl_xor(s0, 32, 64);
            s1 += __shfl_xor(s1, 16, 64); s1 += __shfl_xor(s1, 32, 64);
            s2 += __shfl_xor(s2, 16, 64); s2 += __shfl_xor(s2, 32, 64);
            s3 += __shfl_xor(s3, 16, 64); s3 += __shfl_xor(s3, 32, 64);
            s4 += __shfl_xor(s4, 16, 64); s4 += __shfl_xor(s4, 32, 64);
            s5 += __shfl_xor(s5, 16, 64); s5 += __shfl_xor(s5, 32, 64);
            s6 += __shfl_xor(s6, 16, 64); s6 += __shfl_xor(s6, 32, 64);
            s7 += __shfl_xor(s7, 16, 64); s7 += __shfl_xor(s7, 32, 64);
            float iv = 0.3f / (float)(dg + 1);
            const float4* bp = (const float4*)(b2 + l * 8);
            float4 bA = bp[0], bB = bp[1];
            float f0 = 0.7f * bflo(sv.x) + iv * s0 + bA.x;  f0 = f0 > 0.f ? f0 : 0.f;
            float f1 = 0.7f * bfhi(sv.x) + iv * s1 + bA.y;  f1 = f1 > 0.f ? f1 : 0.f;
            float f2 = 0.7f * bflo(sv.y) + iv * s2 + bA.z;  f2 = f2 > 0.f ? f2 : 0.f;
            float f3 = 0.7f * bfhi(sv.y) + iv * s3 + bA.w;  f3 = f3 > 0.f ? f3 : 0.f;
            float f4 = 0.7f * bflo(sv.z) + iv * s4 + bB.x;  f4 = f4 > 0.f ? f4 : 0.f;
            float f5 = 0.7f * bfhi(sv.z) + iv * s5 + bB.y;  f5 = f5 > 0.f ? f5 : 0.f;
            float f6 = 0.7f * bflo(sv.w) + iv * s6 + bB.z;  f6 = f6 > 0.f ? f6 : 0.f;
            float f7 = 0.7f * bfhi(sv.w) + iv * s7 + bB.w;  f7 = f7 > 0.f ? f7 : 0.f;
            float* orow = out + (size_t)t * H2 + l * 8;
            if (quad == 0) *(float4*)orow = make_float4(f0, f1, f2, f3);
            else if (quad == 1) *(float4*)(orow + 4) = make_float4(f4, f5, f6, f7);
            else if (quad == 2) *(float4*)(&sout[nl][l * 8]) = make_float4(f0, f1, f2, f3);
            else *(float4*)(&sout[nl][l * 8 + 4]) = make_float4(f4, f5, f6, f7);
            // att: lane u computes hidden unit u: dot(out_row, Wa1[u]) over K=128
            float acc = ba1[lane];
            const bf16x8* wrow = (const bf16x8*)(wa1b + (size_t)lane * H2);
            const float* srow = sout[nl];
            #pragma unroll
            for (int k8 = 0; k8 < 16; k8++) {
                bf16x8 w = wrow[k8];
                #pragma unroll
                for (int u = 0; u < 8; u++)
                    acc += bf2f(w[u]) * srow[k8 * 8 + u];
            }
            float gg = (acc > 0.f ? acc : 0.f) * Wa2[lane];
            #pragma unroll
            for (int d = 1; d < 64; d <<= 1) gg += __shfl_xor(gg, d, 64);
            if (lane == 0) att[t] = 1.f / (1.f + expf(-gg));
        }
    }
}

extern "C" void kernel_launch(void* const* d_in, const int* in_sizes, int n_in,
                              void* d_out, int out_size, void* d_ws, size_t ws_size,
                              hipStream_t stream) {
    const float* x   = (const float*)d_in[0];
    const int*   ei  = (const int*)d_in[1];
    const float* W1  = (const float*)d_in[2];
    const float* b1  = (const float*)d_in[3];
    const float* W2  = (const float*)d_in[4];
    const float* b2  = (const float*)d_in[5];
    const float* Wa1 = (const float*)d_in[6];
    const float* ba1 = (const float*)d_in[7];
    const float* Wa2 = (const float*)d_in[8];
    const float* ba2 = (const float*)d_in[9];
    const int* srcv = ei;
    const int* tgt  = ei + E_EDGES;

    float* out_mat = (float*)d_out;                 // N x 128
    float* att     = out_mat + N_NODES * H2;        // N x 1

    // workspace layout
    unsigned short* w1b  = (unsigned short*)d_ws;                // H1*F_IN (frag-linear)
    unsigned short* w2b  = w1b + (size_t)H1 * F_IN;              // H2*H1   (frag-linear)
    unsigned short* wa1b = w2b + (size_t)H2 * H1;                // ATT1*H2 (row-major)
    unsigned short* z0   = wa1b + (size_t)ATT1 * H2;             // N*128
    unsigned short* z1   = z0 + (size_t)N_NODES * H2;            // N*128
    int* cursor = (int*)(z1 + (size_t)N_NODES * H2);             // N
    int* csrf   = cursor + N_NODES;                              // N*DSTRIDE
    int* bar    = csrf + (size_t)N_NODES * DSTRIDE;              // 3 slots x 64 ints

    hipMemsetAsync(bar, 0, 1024, stream);   // barrier slots must be zero each launch

    k_fused<<<NBLK, NTHR, 0, stream>>>(x, srcv, tgt, W1, b1, W2, b2, Wa1, ba1, Wa2, ba2,
                                       w1b, w2b, wa1b, z0, z1, cursor, csrf, bar,
                                       out_mat, att);
}

// Round 6
// 180.228 us; speedup vs baseline: 4.2038x; 1.4021x over previous
//
#include <hip/hip_runtime.h>
#include <hip/hip_bf16.h>
#include <math.h>

#define N_NODES 10000
#define E_EDGES 320000
#define F_IN    384
#define H1      256
#define H2      128
#define ATT1    64
#define DSTRIDE 128   // fixed CSR stride; P(deg>=128) ~ 4e-32 for Binomial(320k, 1e-4)

typedef __attribute__((ext_vector_type(8))) short bf16x8;
typedef __attribute__((ext_vector_type(4))) float f32x4;

static __device__ inline unsigned short f2bf(float f) {
    unsigned u = __float_as_uint(f);
    unsigned r = (u + 0x7fffu + ((u >> 16) & 1u)) >> 16;   // RNE
    return (unsigned short)r;
}

static __device__ inline unsigned pk2bf(float a, float b) {
    __hip_bfloat162 h2 = __float22bfloat162_rn(make_float2(a, b));
    return *reinterpret_cast<unsigned*>(&h2);   // v_cvt_pk_bf16_f32
}

static __device__ inline float bflo(unsigned v) { return __uint_as_float(v << 16); }
static __device__ inline float bfhi(unsigned v) { return __uint_as_float(v & 0xffff0000u); }

// build a bf16x8 MFMA B-fragment from 8 consecutive fp32 weights (same RNE
// rounding as the old k_conv repack -> bit-identical GEMM results, no repack pass)
static __device__ inline bf16x8 ldw8(const float* p) {
    float4 u0 = *(const float4*)p;
    float4 u1 = *(const float4*)(p + 4);
    union { unsigned u[4]; bf16x8 v; } r;
    r.u[0] = pk2bf(u0.x, u0.y); r.u[1] = pk2bf(u0.z, u0.w);
    r.u[2] = pk2bf(u1.x, u1.y); r.u[3] = pk2bf(u1.z, u1.w);
    return r.v;
}

// ---------- fused: fc1+proj GEMM (32-row blocks) + fixed-stride CSR fill
#define NBLK_FC  313                             // 312 full 32-row blocks + 1 ragged 16-row
#define NBLK_FIL ((E_EDGES + 1023) / 1024)       // 313 (4 edges/thread)
#define XS 392   // LDS row stride (ushorts) for the 32x384 x tile
#define S1 264   // LDS row stride (ushorts) for the 32x256 h tile
__global__ __launch_bounds__(256) void k_fc12fill(const float* __restrict__ x,
                                                  const float* __restrict__ W1,
                                                  const float* __restrict__ b1,
                                                  const float* __restrict__ W2,
                                                  unsigned short* __restrict__ z,
                                                  const int* __restrict__ srcv,
                                                  const int* __restrict__ tgt,
                                                  int* __restrict__ cursor,
                                                  unsigned short* __restrict__ csrf) {
    __shared__ unsigned short smem[32 * XS];   // 24.5 KB: x tile; reused for h tile
    if (blockIdx.x >= NBLK_FC) {
        int e0 = (blockIdx.x - NBLK_FC) * 1024 + threadIdx.x;
        #pragma unroll
        for (int q = 0; q < 4; q++) {
            int e = e0 + q * 256;
            if (e < E_EDGES) {
                int t = tgt[e];
                int p = atomicAdd(&cursor[t], 1);
                if (p < DSTRIDE) csrf[t * DSTRIDE + p] = (unsigned short)srcv[e];
            }
        }
        return;
    }
    int wave = threadIdx.x >> 6;
    int lane = threadIdx.x & 63;
    int m0 = blockIdx.x * 32;
    int rows = N_NODES - m0; if (rows > 32) rows = 32;   // 32 (or 16 for last block)
    int ml = lane & 15, quad = lane >> 4;
    {   // stage x tile: up to 32 rows x 384 fp32 -> bf16 LDS, coalesced
        const float4* xsrc = (const float4*)(x + (size_t)m0 * F_IN);
        #pragma unroll
        for (int r = 0; r < 12; r++) {
            int idx = r * 256 + threadIdx.x;
            int row = idx / 96, c4 = idx - row * 96;
            unsigned* sp = (unsigned*)(smem + row * XS + c4 * 4);
            if (row < rows) {
                float4 v = xsrc[idx];
                sp[0] = pk2bf(v.x, v.y);
                sp[1] = pk2bf(v.z, v.w);
            } else {
                sp[0] = 0u; sp[1] = 0u;
            }
        }
    }
    __syncthreads();
    f32x4 acc0[4] = {{0,0,0,0},{0,0,0,0},{0,0,0,0},{0,0,0,0}};
    f32x4 acc1[4] = {{0,0,0,0},{0,0,0,0},{0,0,0,0},{0,0,0,0}};
    {   // stage 1 K-loop: two 16-row A-frags share each B-frag; B built fp32-direct
        const unsigned short* ax0 = smem + ml * XS + quad * 8;
        const unsigned short* ax1 = smem + (16 + ml) * XS + quad * 8;
        for (int kk = 0; kk < F_IN / 32; kk++) {
            bf16x8 a0 = *(const bf16x8*)(ax0 + kk * 32);
            bf16x8 a1 = *(const bf16x8*)(ax1 + kk * 32);
            #pragma unroll
            for (int j = 0; j < 4; j++) {
                int jb = wave * 4 + j;
                bf16x8 b = ldw8(W1 + (size_t)(jb * 16 + ml) * F_IN + kk * 32 + quad * 8);
                acc0[j] = __builtin_amdgcn_mfma_f32_16x16x32_bf16(a0, b, acc0[j], 0, 0, 0);
                acc1[j] = __builtin_amdgcn_mfma_f32_16x16x32_bf16(a1, b, acc1[j], 0, 0, 0);
            }
        }
    }
    __syncthreads();
    #pragma unroll
    for (int j = 0; j < 4; j++) {
        int col = wave * 64 + j * 16 + ml;
        float bb = b1[col];
        #pragma unroll
        for (int r = 0; r < 4; r++) {
            int lr = quad * 4 + r;
            float v0 = acc0[j][r] + bb;
            float v1 = acc1[j][r] + bb;
            smem[lr * S1 + col] = f2bf(v0 > 0.f ? v0 : 0.f);
            smem[(16 + lr) * S1 + col] = f2bf(v1 > 0.f ? v1 : 0.f);
        }
    }
    __syncthreads();
    {   // stage 2: z = h @ W2^T  (two row-halves share each B-frag; B fp32-direct)
        int c0 = wave * 32;
        const unsigned short* pA0 = smem + ml * S1 + quad * 8;
        const unsigned short* pA1 = smem + (16 + ml) * S1 + quad * 8;
        f32x4 za00 = {0,0,0,0}, za01 = {0,0,0,0}, za10 = {0,0,0,0}, za11 = {0,0,0,0};
        #pragma unroll
        for (int kk = 0; kk < H1 / 32; kk++) {
            bf16x8 a0 = *(const bf16x8*)(pA0 + kk * 32);
            bf16x8 a1 = *(const bf16x8*)(pA1 + kk * 32);
            bf16x8 b0 = ldw8(W2 + (size_t)((wave * 2 + 0) * 16 + ml) * H1 + kk * 32 + quad * 8);
            bf16x8 b1v = ldw8(W2 + (size_t)((wave * 2 + 1) * 16 + ml) * H1 + kk * 32 + quad * 8);
            za00 = __builtin_amdgcn_mfma_f32_16x16x32_bf16(a0, b0, za00, 0, 0, 0);
            za01 = __builtin_amdgcn_mfma_f32_16x16x32_bf16(a0, b1v, za01, 0, 0, 0);
            za10 = __builtin_amdgcn_mfma_f32_16x16x32_bf16(a1, b0, za10, 0, 0, 0);
            za11 = __builtin_amdgcn_mfma_f32_16x16x32_bf16(a1, b1v, za11, 0, 0, 0);
        }
        #pragma unroll
        for (int r = 0; r < 4; r++) {
            int row0 = m0 + quad * 4 + r;           // always < N_NODES
            z[(size_t)row0 * H2 + c0 + ml] = f2bf(za00[r]);
            z[(size_t)row0 * H2 + c0 + 16 + ml] = f2bf(za01[r]);
            int row1 = row0 + 16;
            if (row1 < N_NODES) {
                z[(size_t)row1 * H2 + c0 + ml] = f2bf(za10[r]);
                z[(size_t)row1 * H2 + c0 + 16 + ml] = f2bf(za11[r]);
            }
        }
    }
}

#define ACC8(v) { s0 += bflo(v.x); s1 += bfhi(v.x); s2 += bflo(v.y); s3 += bfhi(v.y); \
                  s4 += bflo(v.z); s5 += bfhi(v.z); s6 += bflo(v.w); s7 += bfhi(v.w); }

// ---------- agg pass 1, uint4 gather: 16 lanes/row, 16 edges / 4 loads per iteration
__global__ __launch_bounds__(256) void k_agg1(const unsigned short* __restrict__ zin,
                                              unsigned short* __restrict__ zout,
                                              const int* __restrict__ cursor,
                                              const unsigned short* __restrict__ csrf) {
    int t = blockIdx.x * 4 + (threadIdx.x >> 6);
    int lane = threadIdx.x & 63;
    int l = lane & 15, quad = lane >> 4;
    int dg = cursor[t];
    if (dg > DSTRIDE) dg = DSTRIDE;
    const uint4* base = (const uint4*)zin;
    uint4 sv = make_uint4(0, 0, 0, 0);
    if (quad == 0) sv = base[(size_t)t * 16 + l];   // prefetch self row early
    float s0=0.f,s1=0.f,s2=0.f,s3=0.f,s4=0.f,s5=0.f,s6=0.f,s7=0.f;
    for (int e0 = 0; e0 < dg; e0 += 64) {
        int cnt = dg - e0; if (cnt > 64) cnt = 64;
        int c = (e0 + lane < dg) ? (int)csrf[t * DSTRIDE + e0 + lane] : 0;
        for (int j = 0; j < cnt; j += 16) {
            int sA = __shfl(c, j + quad, 64);
            int sB = __shfl(c, j + 4 + quad, 64);
            int sC = __shfl(c, j + 8 + quad, 64);
            int sD = __shfl(c, j + 12 + quad, 64);
            uint4 vA = base[(size_t)sA * 16 + l];
            uint4 vB = base[(size_t)sB * 16 + l];
            uint4 vC = base[(size_t)sC * 16 + l];
            uint4 vD = base[(size_t)sD * 16 + l];
            if (j + quad < cnt)      ACC8(vA);
            if (j + 4 + quad < cnt)  ACC8(vB);
            if (j + 8 + quad < cnt)  ACC8(vC);
            if (j + 12 + quad < cnt) ACC8(vD);
        }
    }
    s0 += __shfl_xor(s0, 16, 64); s0 += __shfl_xor(s0, 32, 64);
    s1 += __shfl_xor(s1, 16, 64); s1 += __shfl_xor(s1, 32, 64);
    s2 += __shfl_xor(s2, 16, 64); s2 += __shfl_xor(s2, 32, 64);
    s3 += __shfl_xor(s3, 16, 64); s3 += __shfl_xor(s3, 32, 64);
    s4 += __shfl_xor(s4, 16, 64); s4 += __shfl_xor(s4, 32, 64);
    s5 += __shfl_xor(s5, 16, 64); s5 += __shfl_xor(s5, 32, 64);
    s6 += __shfl_xor(s6, 16, 64); s6 += __shfl_xor(s6, 32, 64);
    s7 += __shfl_xor(s7, 16, 64); s7 += __shfl_xor(s7, 32, 64);
    if (quad == 0) {
        float iv = 0.3f / (float)(dg + 1);
        uint4 o;
        o.x = pk2bf(0.7f * bflo(sv.x) + iv * s0, 0.7f * bfhi(sv.x) + iv * s1);
        o.y = pk2bf(0.7f * bflo(sv.y) + iv * s2, 0.7f * bfhi(sv.y) + iv * s3);
        o.z = pk2bf(0.7f * bflo(sv.z) + iv * s4, 0.7f * bfhi(sv.z) + iv * s5);
        o.w = pk2bf(0.7f * bflo(sv.w) + iv * s6, 0.7f * bfhi(sv.w) + iv * s7);
        ((uint4*)zout)[(size_t)t * 16 + l] = o;   // stays in L2: pass 2's gather table
    }
}

// ---------- agg pass 2 + epilogue, out fp32 + att head (Wa1 consumed fp32-direct)
__global__ __launch_bounds__(256) void k_agg2fin(const unsigned short* __restrict__ zin,
                                                 const int* __restrict__ cursor,
                                                 const unsigned short* __restrict__ csrf,
                                                 const float* __restrict__ b2,
                                                 const float* __restrict__ Wa1,
                                                 const float* __restrict__ ba1,
                                                 const float* __restrict__ Wa2,
                                                 const float* __restrict__ ba2,
                                                 float* __restrict__ out,
                                                 float* __restrict__ att) {
    __shared__ float sout[4][128];
    int nl = threadIdx.x >> 6;
    int t = blockIdx.x * 4 + nl;
    int lane = threadIdx.x & 63;
    int l = lane & 15, quad = lane >> 4;
    int dg = cursor[t];
    if (dg > DSTRIDE) dg = DSTRIDE;
    const uint4* base = (const uint4*)zin;
    uint4 sv = base[(size_t)t * 16 + l];   // prefetch self row (all quads need it)
    float s0=0.f,s1=0.f,s2=0.f,s3=0.f,s4=0.f,s5=0.f,s6=0.f,s7=0.f;
    for (int e0 = 0; e0 < dg; e0 += 64) {
        int cnt = dg - e0; if (cnt > 64) cnt = 64;
        int c = (e0 + lane < dg) ? (int)csrf[t * DSTRIDE + e0 + lane] : 0;
        for (int j = 0; j < cnt; j += 16) {
            int sA = __shfl(c, j + quad, 64);
            int sB = __shfl(c, j + 4 + quad, 64);
            int sC = __shfl(c, j + 8 + quad, 64);
            int sD = __shfl(c, j + 12 + quad, 64);
            uint4 vA = base[(size_t)sA * 16 + l];
            uint4 vB = base[(size_t)sB * 16 + l];
            uint4 vC = base[(size_t)sC * 16 + l];
            uint4 vD = base[(size_t)sD * 16 + l];
            if (j + quad < cnt)      ACC8(vA);
            if (j + 4 + quad < cnt)  ACC8(vB);
            if (j + 8 + quad < cnt)  ACC8(vC);
            if (j + 12 + quad < cnt) ACC8(vD);
        }
    }
    s0 += __shfl_xor(s0, 16, 64); s0 += __shfl_xor(s0, 32, 64);
    s1 += __shfl_xor(s1, 16, 64); s1 += __shfl_xor(s1, 32, 64);
    s2 += __shfl_xor(s2, 16, 64); s2 += __shfl_xor(s2, 32, 64);
    s3 += __shfl_xor(s3, 16, 64); s3 += __shfl_xor(s3, 32, 64);
    s4 += __shfl_xor(s4, 16, 64); s4 += __shfl_xor(s4, 32, 64);
    s5 += __shfl_xor(s5, 16, 64); s5 += __shfl_xor(s5, 32, 64);
    s6 += __shfl_xor(s6, 16, 64); s6 += __shfl_xor(s6, 32, 64);
    s7 += __shfl_xor(s7, 16, 64); s7 += __shfl_xor(s7, 32, 64);
    // epilogue: all quads hold full sums for cols l*8..l*8+7
    float iv = 0.3f / (float)(dg + 1);
    const float4* bp = (const float4*)(b2 + l * 8);
    float4 bA = bp[0], bB = bp[1];
    float f0 = 0.7f * bflo(sv.x) + iv * s0 + bA.x;  f0 = f0 > 0.f ? f0 : 0.f;
    float f1 = 0.7f * bfhi(sv.x) + iv * s1 + bA.y;  f1 = f1 > 0.f ? f1 : 0.f;
    float f2 = 0.7f * bflo(sv.y) + iv * s2 + bA.z;  f2 = f2 > 0.f ? f2 : 0.f;
    float f3 = 0.7f * bfhi(sv.y) + iv * s3 + bA.w;  f3 = f3 > 0.f ? f3 : 0.f;
    float f4 = 0.7f * bflo(sv.z) + iv * s4 + bB.x;  f4 = f4 > 0.f ? f4 : 0.f;
    float f5 = 0.7f * bfhi(sv.z) + iv * s5 + bB.y;  f5 = f5 > 0.f ? f5 : 0.f;
    float f6 = 0.7f * bflo(sv.w) + iv * s6 + bB.z;  f6 = f6 > 0.f ? f6 : 0.f;
    float f7 = 0.7f * bfhi(sv.w) + iv * s7 + bB.w;  f7 = f7 > 0.f ? f7 : 0.f;
    // quads split the stores: q0/q1 -> global out, q2/q3 -> LDS for att
    float* orow = out + (size_t)t * H2 + l * 8;
    if (quad == 0) *(float4*)orow = make_float4(f0, f1, f2, f3);
    else if (quad == 1) *(float4*)(orow + 4) = make_float4(f4, f5, f6, f7);
    else if (quad == 2) *(float4*)(&sout[nl][l * 8]) = make_float4(f0, f1, f2, f3);
    else *(float4*)(&sout[nl][l * 8 + 4]) = make_float4(f4, f5, f6, f7);
    // att: lane u computes hidden unit u: dot(out_row, Wa1[u]) over K=128, fp32
    float acc = ba1[lane];
    const float4* wrow = (const float4*)(Wa1 + (size_t)lane * H2);
    const float* srow = sout[nl];
    #pragma unroll
    for (int k4 = 0; k4 < 32; k4++) {
        float4 w = wrow[k4];
        acc += w.x * srow[k4 * 4 + 0] + w.y * srow[k4 * 4 + 1]
             + w.z * srow[k4 * 4 + 2] + w.w * srow[k4 * 4 + 3];
    }
    float g = (acc > 0.f ? acc : 0.f) * Wa2[lane];
    #pragma unroll
    for (int d = 1; d < 64; d <<= 1) g += __shfl_xor(g, d, 64);
    if (lane == 0) att[t] = 1.f / (1.f + expf(-(g + ba2[0])));
}

extern "C" void kernel_launch(void* const* d_in, const int* in_sizes, int n_in,
                              void* d_out, int out_size, void* d_ws, size_t ws_size,
                              hipStream_t stream) {
    const float* x   = (const float*)d_in[0];
    const int*   ei  = (const int*)d_in[1];
    const float* W1  = (const float*)d_in[2];
    const float* b1  = (const float*)d_in[3];
    const float* W2  = (const float*)d_in[4];
    const float* b2  = (const float*)d_in[5];
    const float* Wa1 = (const float*)d_in[6];
    const float* ba1 = (const float*)d_in[7];
    const float* Wa2 = (const float*)d_in[8];
    const float* ba2 = (const float*)d_in[9];
    const int* srcv = ei;
    const int* tgt  = ei + E_EDGES;

    float* out_mat = (float*)d_out;                 // N x 128
    float* att     = out_mat + N_NODES * H2;        // N x 1

    // workspace layout (no weight repacks anymore)
    unsigned short* z0 = (unsigned short*)d_ws;                   // N*128 bf16
    unsigned short* z1 = z0 + (size_t)N_NODES * H2;               // N*128 bf16
    int* cursor = (int*)(z1 + (size_t)N_NODES * H2);              // N ints
    unsigned short* csrf = (unsigned short*)(cursor + N_NODES);   // N*DSTRIDE ushort

    // zero in-degree cursors (40 KB, replaces the k_conv launch's zeroing duty)
    hipMemsetAsync(cursor, 0, N_NODES * sizeof(int), stream);

    // fused fc1+proj GEMM (313 blocks, M=32, fp32-direct weights) + CSR fill (313 blocks)
    k_fc12fill<<<NBLK_FC + NBLK_FIL, 256, 0, stream>>>(x, W1, b1, W2, z0,
                                                       srcv, tgt, cursor, csrf);

    // agg pass 1 (z0 -> z1)
    k_agg1<<<N_NODES / 4, 256, 0, stream>>>(z0, z1, cursor, csrf);

    // agg pass 2 + bias/relu -> out, att head -> att
    k_agg2fin<<<N_NODES / 4, 256, 0, stream>>>(z1, cursor, csrf, b2,
                                               Wa1, ba1, Wa2, ba2, out_mat, att);
}

// Round 7
// 162.617 us; speedup vs baseline: 4.6591x; 1.1083x over previous
//
#include <hip/hip_runtime.h>
#include <hip/hip_bf16.h>
#include <math.h>

#define N_NODES 10000
#define E_EDGES 320000
#define F_IN    384
#define H1      256
#define H2      128
#define ATT1    64
#define DSTRIDE 128   // fixed CSR stride; P(deg>=128) ~ 4e-32 for Binomial(320k, 1e-4)

typedef __attribute__((ext_vector_type(8))) short bf16x8;
typedef __attribute__((ext_vector_type(4))) float f32x4;

static __device__ inline unsigned short f2bf(float f) {
    unsigned u = __float_as_uint(f);
    unsigned r = (u + 0x7fffu + ((u >> 16) & 1u)) >> 16;   // RNE
    return (unsigned short)r;
}

static __device__ inline unsigned pk2bf(float a, float b) {
    __hip_bfloat162 h2 = __float22bfloat162_rn(make_float2(a, b));
    return *reinterpret_cast<unsigned*>(&h2);   // v_cvt_pk_bf16_f32
}

static __device__ inline float bflo(unsigned v) { return __uint_as_float(v << 16); }
static __device__ inline float bfhi(unsigned v) { return __uint_as_float(v & 0xffff0000u); }

// ---------- k_conv: frag-linear weight repacks + cursor zeroing
#define NW1 (H1 * F_IN / 8)   // 12288 uint4 slots
#define NW2 (H2 * H1 / 8)     // 4096
#define NCZ (N_NODES / 4)     // 2500 int4 zeroes
__global__ void k_conv(const float* __restrict__ W1, const float* __restrict__ W2,
                       unsigned short* __restrict__ w1b, unsigned short* __restrict__ w2b,
                       int* __restrict__ cursor) {
    int i = blockIdx.x * blockDim.x + threadIdx.x;
    if (i < NW1) {
        int s = i;
        int jb = s / 768, rem = s - jb * 768;
        int kk = rem >> 6, lane = rem & 63;
        int ml = lane & 15, quad = lane >> 4;
        const float* p = W1 + (size_t)(jb * 16 + ml) * F_IN + kk * 32 + quad * 8;
        float4 u0 = *(const float4*)p;
        float4 u1 = *(const float4*)(p + 4);
        uint4 o;
        o.x = pk2bf(u0.x, u0.y); o.y = pk2bf(u0.z, u0.w);
        o.z = pk2bf(u1.x, u1.y); o.w = pk2bf(u1.z, u1.w);
        ((uint4*)w1b)[s] = o;
    } else if (i < NW1 + NW2) {
        int s = i - NW1;
        int jcol = s / 512, rem = s - jcol * 512;
        int kk = rem >> 6, lane = rem & 63;
        int ml = lane & 15, quad = lane >> 4;
        const float* p = W2 + (size_t)(jcol * 16 + ml) * H1 + kk * 32 + quad * 8;
        float4 u0 = *(const float4*)p;
        float4 u1 = *(const float4*)(p + 4);
        uint4 o;
        o.x = pk2bf(u0.x, u0.y); o.y = pk2bf(u0.z, u0.w);
        o.z = pk2bf(u1.x, u1.y); o.w = pk2bf(u1.z, u1.w);
        ((uint4*)w2b)[s] = o;
    } else {
        int j = i - NW1 - NW2;
        if (j < NCZ) ((int4*)cursor)[j] = make_int4(0, 0, 0, 0);
    }
}

// ---------- fused: fc1+proj GEMM (32-row blocks) + fixed-stride CSR fill
#define NBLK_FC  313                             // 312 full 32-row blocks + 1 ragged 16-row
#define NBLK_FIL ((E_EDGES + 1023) / 1024)       // 313 (4 edges/thread)
#define XS 392   // LDS row stride (ushorts) for the 32x384 x tile
#define S1 264   // LDS row stride (ushorts) for the 32x256 h tile
__global__ __launch_bounds__(256) void k_fc12fill(const float* __restrict__ x,
                                                  const unsigned short* __restrict__ w1b,
                                                  const float* __restrict__ b1,
                                                  const unsigned short* __restrict__ w2b,
                                                  unsigned short* __restrict__ z,
                                                  const int* __restrict__ srcv,
                                                  const int* __restrict__ tgt,
                                                  int* __restrict__ cursor,
                                                  int* __restrict__ csrf) {
    __shared__ unsigned short smem[32 * XS];   // 24.5 KB: x tile; reused for h tile
    if (blockIdx.x >= NBLK_FC) {
        int e0 = (blockIdx.x - NBLK_FC) * 1024 + threadIdx.x;
        #pragma unroll
        for (int q = 0; q < 4; q++) {
            int e = e0 + q * 256;
            if (e < E_EDGES) {
                int t = tgt[e];
                int p = atomicAdd(&cursor[t], 1);
                if (p < DSTRIDE) csrf[t * DSTRIDE + p] = srcv[e];   // plain store: stay in L2
            }
        }
        return;
    }
    int wave = threadIdx.x >> 6;
    int lane = threadIdx.x & 63;
    int m0 = blockIdx.x * 32;
    int rows = N_NODES - m0; if (rows > 32) rows = 32;   // 32 (or 16 for last block)
    int ml = lane & 15, quad = lane >> 4;
    {   // stage x tile: up to 32 rows x 384 fp32 -> bf16 LDS, coalesced
        const float4* xsrc = (const float4*)(x + (size_t)m0 * F_IN);
        #pragma unroll
        for (int r = 0; r < 12; r++) {
            int idx = r * 256 + threadIdx.x;
            int row = idx / 96, c4 = idx - row * 96;
            unsigned* sp = (unsigned*)(smem + row * XS + c4 * 4);
            if (row < rows) {
                float4 v = xsrc[idx];
                sp[0] = pk2bf(v.x, v.y);
                sp[1] = pk2bf(v.z, v.w);
            } else {
                sp[0] = 0u; sp[1] = 0u;
            }
        }
    }
    __syncthreads();
    f32x4 acc0[4] = {{0,0,0,0},{0,0,0,0},{0,0,0,0},{0,0,0,0}};
    f32x4 acc1[4] = {{0,0,0,0},{0,0,0,0},{0,0,0,0},{0,0,0,0}};
    {   // stage 1 K-loop: two 16-row A-frags share each B-frag (2x MFMA per B load)
        const unsigned short* ax0 = smem + ml * XS + quad * 8;
        const unsigned short* ax1 = smem + (16 + ml) * XS + quad * 8;
        const bf16x8* W1f = (const bf16x8*)w1b;
        for (int kk = 0; kk < F_IN / 32; kk++) {
            bf16x8 a0 = *(const bf16x8*)(ax0 + kk * 32);
            bf16x8 a1 = *(const bf16x8*)(ax1 + kk * 32);
            #pragma unroll
            for (int j = 0; j < 4; j++) {
                int jb = wave * 4 + j;
                bf16x8 b = W1f[(jb * 12 + kk) * 64 + lane];
                acc0[j] = __builtin_amdgcn_mfma_f32_16x16x32_bf16(a0, b, acc0[j], 0, 0, 0);
                acc1[j] = __builtin_amdgcn_mfma_f32_16x16x32_bf16(a1, b, acc1[j], 0, 0, 0);
            }
        }
    }
    __syncthreads();
    #pragma unroll
    for (int j = 0; j < 4; j++) {
        int col = wave * 64 + j * 16 + ml;
        float bb = b1[col];
        #pragma unroll
        for (int r = 0; r < 4; r++) {
            int lr = quad * 4 + r;
            float v0 = acc0[j][r] + bb;
            float v1 = acc1[j][r] + bb;
            smem[lr * S1 + col] = f2bf(v0 > 0.f ? v0 : 0.f);
            smem[(16 + lr) * S1 + col] = f2bf(v1 > 0.f ? v1 : 0.f);
        }
    }
    __syncthreads();
    {   // stage 2: z = h @ W2^T  (two row-halves share each B-frag)
        int c0 = wave * 32;
        const unsigned short* pA0 = smem + ml * S1 + quad * 8;
        const unsigned short* pA1 = smem + (16 + ml) * S1 + quad * 8;
        const bf16x8* W2f = (const bf16x8*)w2b;
        f32x4 za00 = {0,0,0,0}, za01 = {0,0,0,0}, za10 = {0,0,0,0}, za11 = {0,0,0,0};
        #pragma unroll
        for (int kk = 0; kk < H1 / 32; kk++) {
            bf16x8 a0 = *(const bf16x8*)(pA0 + kk * 32);
            bf16x8 a1 = *(const bf16x8*)(pA1 + kk * 32);
            bf16x8 b0 = W2f[((wave * 2 + 0) * 8 + kk) * 64 + lane];
            bf16x8 b1v = W2f[((wave * 2 + 1) * 8 + kk) * 64 + lane];
            za00 = __builtin_amdgcn_mfma_f32_16x16x32_bf16(a0, b0, za00, 0, 0, 0);
            za01 = __builtin_amdgcn_mfma_f32_16x16x32_bf16(a0, b1v, za01, 0, 0, 0);
            za10 = __builtin_amdgcn_mfma_f32_16x16x32_bf16(a1, b0, za10, 0, 0, 0);
            za11 = __builtin_amdgcn_mfma_f32_16x16x32_bf16(a1, b1v, za11, 0, 0, 0);
        }
        #pragma unroll
        for (int r = 0; r < 4; r++) {
            int row0 = m0 + quad * 4 + r;           // always < N_NODES
            z[(size_t)row0 * H2 + c0 + ml] = f2bf(za00[r]);
            z[(size_t)row0 * H2 + c0 + 16 + ml] = f2bf(za01[r]);
            int row1 = row0 + 16;
            if (row1 < N_NODES) {
                z[(size_t)row1 * H2 + c0 + ml] = f2bf(za10[r]);
                z[(size_t)row1 * H2 + c0 + 16 + ml] = f2bf(za11[r]);
            }
        }
    }
}

#define ACC8(v) { s0 += bflo(v.x); s1 += bfhi(v.x); s2 += bflo(v.y); s3 += bfhi(v.y); \
                  s4 += bflo(v.z); s5 += bfhi(v.z); s6 += bflo(v.w); s7 += bfhi(v.w); }

// Fully-unrolled 64-edge gather chunk: compile-time j loop -> all 16 uint4 loads
// in flight (one L2/HBM latency round per chunk instead of 2-4). Loads are
// unconditional (c zero-padded -> padding lanes hit the hot row-0 lines); only
// the adds are predicated. dg<=64 covers all rows but ~1e-4 expected count.
#define GATHER64()                                                          \
    for (int e0 = 0; e0 < dg; e0 += 64) {                                   \
        int cnt = dg - e0; if (cnt > 64) cnt = 64;                          \
        int c = (e0 + lane < dg) ? csrf[t * DSTRIDE + e0 + lane] : 0;       \
        _Pragma("unroll")                                                   \
        for (int j = 0; j < 64; j += 16) {                                  \
            int sA = __shfl(c, j + quad, 64);                               \
            int sB = __shfl(c, j + 4 + quad, 64);                           \
            int sC = __shfl(c, j + 8 + quad, 64);                           \
            int sD = __shfl(c, j + 12 + quad, 64);                          \
            uint4 vA = base[(size_t)sA * 16 + l];                           \
            uint4 vB = base[(size_t)sB * 16 + l];                           \
            uint4 vC = base[(size_t)sC * 16 + l];                           \
            uint4 vD = base[(size_t)sD * 16 + l];                           \
            if (j + quad < cnt)      ACC8(vA);                              \
            if (j + 4 + quad < cnt)  ACC8(vB);                              \
            if (j + 8 + quad < cnt)  ACC8(vC);                              \
            if (j + 12 + quad < cnt) ACC8(vD);                              \
        }                                                                   \
    }

#define QUADRED()                                                           \
    s0 += __shfl_xor(s0, 16, 64); s0 += __shfl_xor(s0, 32, 64);             \
    s1 += __shfl_xor(s1, 16, 64); s1 += __shfl_xor(s1, 32, 64);             \
    s2 += __shfl_xor(s2, 16, 64); s2 += __shfl_xor(s2, 32, 64);             \
    s3 += __shfl_xor(s3, 16, 64); s3 += __shfl_xor(s3, 32, 64);             \
    s4 += __shfl_xor(s4, 16, 64); s4 += __shfl_xor(s4, 32, 64);             \
    s5 += __shfl_xor(s5, 16, 64); s5 += __shfl_xor(s5, 32, 64);             \
    s6 += __shfl_xor(s6, 16, 64); s6 += __shfl_xor(s6, 32, 64);             \
    s7 += __shfl_xor(s7, 16, 64); s7 += __shfl_xor(s7, 32, 64);

// ---------- agg pass 1 (z0 -> z1)
__global__ __launch_bounds__(256) void k_agg1(const unsigned short* __restrict__ zin,
                                              unsigned short* __restrict__ zout,
                                              const int* __restrict__ cursor,
                                              const int* __restrict__ csrf) {
    int t = blockIdx.x * 4 + (threadIdx.x >> 6);
    int lane = threadIdx.x & 63;
    int l = lane & 15, quad = lane >> 4;
    int dg = cursor[t];
    if (dg > DSTRIDE) dg = DSTRIDE;
    const uint4* base = (const uint4*)zin;
    uint4 sv = make_uint4(0, 0, 0, 0);
    if (quad == 0) sv = base[(size_t)t * 16 + l];   // prefetch self row early
    float s0=0.f,s1=0.f,s2=0.f,s3=0.f,s4=0.f,s5=0.f,s6=0.f,s7=0.f;
    GATHER64();
    QUADRED();
    if (quad == 0) {
        float iv = 0.3f / (float)(dg + 1);
        uint4 o;
        o.x = pk2bf(0.7f * bflo(sv.x) + iv * s0, 0.7f * bfhi(sv.x) + iv * s1);
        o.y = pk2bf(0.7f * bflo(sv.y) + iv * s2, 0.7f * bfhi(sv.y) + iv * s3);
        o.z = pk2bf(0.7f * bflo(sv.z) + iv * s4, 0.7f * bfhi(sv.z) + iv * s5);
        o.w = pk2bf(0.7f * bflo(sv.w) + iv * s6, 0.7f * bfhi(sv.w) + iv * s7);
        ((uint4*)zout)[(size_t)t * 16 + l] = o;   // stays in L2: pass 2's gather table
    }
}

// ---------- agg pass 2 + epilogue, out fp32 + att head (fp32 Wa1, + ba2)
__global__ __launch_bounds__(256) void k_agg2fin(const unsigned short* __restrict__ zin,
                                                 const int* __restrict__ cursor,
                                                 const int* __restrict__ csrf,
                                                 const float* __restrict__ b2,
                                                 const float* __restrict__ Wa1,
                                                 const float* __restrict__ ba1,
                                                 const float* __restrict__ Wa2,
                                                 const float* __restrict__ ba2,
                                                 float* __restrict__ out,
                                                 float* __restrict__ att) {
    __shared__ float sout[4][128];
    int nl = threadIdx.x >> 6;
    int t = blockIdx.x * 4 + nl;
    int lane = threadIdx.x & 63;
    int l = lane & 15, quad = lane >> 4;
    int dg = cursor[t];
    if (dg > DSTRIDE) dg = DSTRIDE;
    const uint4* base = (const uint4*)zin;
    uint4 sv = base[(size_t)t * 16 + l];   // prefetch self row (all quads need it)
    float s0=0.f,s1=0.f,s2=0.f,s3=0.f,s4=0.f,s5=0.f,s6=0.f,s7=0.f;
    GATHER64();
    QUADRED();
    // epilogue: all quads hold full sums for cols l*8..l*8+7
    float iv = 0.3f / (float)(dg + 1);
    const float4* bp = (const float4*)(b2 + l * 8);
    float4 bA = bp[0], bB = bp[1];
    float f0 = 0.7f * bflo(sv.x) + iv * s0 + bA.x;  f0 = f0 > 0.f ? f0 : 0.f;
    float f1 = 0.7f * bfhi(sv.x) + iv * s1 + bA.y;  f1 = f1 > 0.f ? f1 : 0.f;
    float f2 = 0.7f * bflo(sv.y) + iv * s2 + bA.z;  f2 = f2 > 0.f ? f2 : 0.f;
    float f3 = 0.7f * bfhi(sv.y) + iv * s3 + bA.w;  f3 = f3 > 0.f ? f3 : 0.f;
    float f4 = 0.7f * bflo(sv.z) + iv * s4 + bB.x;  f4 = f4 > 0.f ? f4 : 0.f;
    float f5 = 0.7f * bfhi(sv.z) + iv * s5 + bB.y;  f5 = f5 > 0.f ? f5 : 0.f;
    float f6 = 0.7f * bflo(sv.w) + iv * s6 + bB.z;  f6 = f6 > 0.f ? f6 : 0.f;
    float f7 = 0.7f * bfhi(sv.w) + iv * s7 + bB.w;  f7 = f7 > 0.f ? f7 : 0.f;
    // quads split the stores: q0/q1 -> global out, q2/q3 -> LDS for att
    float* orow = out + (size_t)t * H2 + l * 8;
    if (quad == 0) *(float4*)orow = make_float4(f0, f1, f2, f3);
    else if (quad == 1) *(float4*)(orow + 4) = make_float4(f4, f5, f6, f7);
    else if (quad == 2) *(float4*)(&sout[nl][l * 8]) = make_float4(f0, f1, f2, f3);
    else *(float4*)(&sout[nl][l * 8 + 4]) = make_float4(f4, f5, f6, f7);
    // att: lane u computes hidden unit u: dot(out_row, Wa1[u]) over K=128, fp32
    float acc = ba1[lane];
    const float4* wrow = (const float4*)(Wa1 + (size_t)lane * H2);
    const float* srow = sout[nl];
    #pragma unroll
    for (int k4 = 0; k4 < 32; k4++) {
        float4 w = wrow[k4];
        acc += w.x * srow[k4 * 4 + 0] + w.y * srow[k4 * 4 + 1]
             + w.z * srow[k4 * 4 + 2] + w.w * srow[k4 * 4 + 3];
    }
    float g = (acc > 0.f ? acc : 0.f) * Wa2[lane];
    #pragma unroll
    for (int d = 1; d < 64; d <<= 1) g += __shfl_xor(g, d, 64);
    if (lane == 0) att[t] = 1.f / (1.f + expf(-(g + ba2[0])));
}

extern "C" void kernel_launch(void* const* d_in, const int* in_sizes, int n_in,
                              void* d_out, int out_size, void* d_ws, size_t ws_size,
                              hipStream_t stream) {
    const float* x   = (const float*)d_in[0];
    const int*   ei  = (const int*)d_in[1];
    const float* W1  = (const float*)d_in[2];
    const float* b1  = (const float*)d_in[3];
    const float* W2  = (const float*)d_in[4];
    const float* b2  = (const float*)d_in[5];
    const float* Wa1 = (const float*)d_in[6];
    const float* ba1 = (const float*)d_in[7];
    const float* Wa2 = (const float*)d_in[8];
    const float* ba2 = (const float*)d_in[9];
    const int* srcv = ei;
    const int* tgt  = ei + E_EDGES;

    float* out_mat = (float*)d_out;                 // N x 128
    float* att     = out_mat + N_NODES * H2;        // N x 1

    // workspace layout
    unsigned short* w1b = (unsigned short*)d_ws;                 // H1*F_IN (frag-linear)
    unsigned short* w2b = w1b + (size_t)H1 * F_IN;               // H2*H1   (frag-linear)
    unsigned short* z0  = w2b + (size_t)H2 * H1;                 // N*128 bf16
    unsigned short* z1  = z0 + (size_t)N_NODES * H2;             // N*128 bf16
    int* cursor = (int*)(z1 + (size_t)N_NODES * H2);             // N ints
    int* csrf   = cursor + N_NODES;                              // N*DSTRIDE ints

    // weight repacks + cursor zeroing (one small launch)
    {
        int total = NW1 + NW2 + NCZ;   // 18884
        k_conv<<<(total + 255) / 256, 256, 0, stream>>>(W1, W2, w1b, w2b, cursor);
    }

    // fused fc1+proj GEMM (313 blocks, M=32) + fixed-stride CSR fill (313 blocks)
    k_fc12fill<<<NBLK_FC + NBLK_FIL, 256, 0, stream>>>(x, w1b, b1, w2b, z0,
                                                       srcv, tgt, cursor, csrf);

    // agg pass 1 (z0 -> z1)
    k_agg1<<<N_NODES / 4, 256, 0, stream>>>(z0, z1, cursor, csrf);

    // agg pass 2 + bias/relu -> out, att head -> att
    k_agg2fin<<<N_NODES / 4, 256, 0, stream>>>(z1, cursor, csrf, b2,
                                               Wa1, ba1, Wa2, ba2, out_mat, att);
}

// Round 8
// 149.631 us; speedup vs baseline: 5.0635x; 1.0868x over previous
//
#include <hip/hip_runtime.h>
#include <hip/hip_bf16.h>
#include <math.h>

#define N_NODES 10000
#define E_EDGES 320000
#define F_IN    384
#define H1      256
#define H2      128
#define ATT1    64
#define DSTRIDE 128   // fixed CSR stride; P(deg>=128) ~ 4e-32 for Binomial(320k, 1e-4)

typedef __attribute__((ext_vector_type(8))) short bf16x8;
typedef __attribute__((ext_vector_type(4))) float f32x4;

static __device__ inline unsigned short f2bf(float f) {
    unsigned u = __float_as_uint(f);
    unsigned r = (u + 0x7fffu + ((u >> 16) & 1u)) >> 16;   // RNE
    return (unsigned short)r;
}

static __device__ inline unsigned pk2bf(float a, float b) {
    __hip_bfloat162 h2 = __float22bfloat162_rn(make_float2(a, b));
    return *reinterpret_cast<unsigned*>(&h2);   // v_cvt_pk_bf16_f32
}

static __device__ inline float bflo(unsigned v) { return __uint_as_float(v << 16); }
static __device__ inline float bfhi(unsigned v) { return __uint_as_float(v & 0xffff0000u); }
static __device__ inline float bf2f(short s) {
    return __uint_as_float(((unsigned)(unsigned short)s) << 16);
}

// ---------- merged kernel role sizes
#define NW1 (H1 * F_IN / 8)            // 12288 uint4 repack slots
#define NW2 (H2 * H1 / 8)              // 4096
#define NWA (ATT1 * H2 / 4)            // 2048 float4 -> ushort4
#define NBLK_CONV ((NW1 + NW2 + NWA) / 256)      // 72 blocks, exactly 1 item/thread
#define NBLK_FC   313                  // 312 full 32-row GEMM blocks + 1 ragged 16-row
#define NBLK_FIL  ((E_EDGES + 1023) / 1024)      // 313 (4 edges/thread)
#define XS 392    // LDS row stride (ushorts) for the 32x384 x tile
#define S1 264    // LDS row stride (ushorts) for the 32x256 h tile

// ---------- merged: weight repack (72) | fc1+proj GEMM (313) | CSR fill (313)
// GEMM blocks consume w1b/w2b produced by conv blocks IN THE SAME LAUNCH via a
// one-shot flag: conv block = {stores, vmcnt(0), syncthreads, release-fence,
// relaxed add}; GEMM block = {stage x-tile (overlaps), relaxed poll, acquire-
// fence}. All 1010 blocks are co-resident (LDS 24.5KB -> 6 blk/CU, 1536 slots)
// so the wait cannot starve; bounded spin as failsafe. This is NOT the round-4
// barrier: one fence pair per block total, no repeated acquire polling.
__global__ __launch_bounds__(256) void k_main(const float* __restrict__ x,
                                              const float* __restrict__ W1,
                                              const float* __restrict__ b1,
                                              const float* __restrict__ W2,
                                              const float* __restrict__ Wa1,
                                              unsigned short* __restrict__ w1b,
                                              unsigned short* __restrict__ w2b,
                                              unsigned short* __restrict__ wa1b,
                                              unsigned short* __restrict__ z,
                                              const int* __restrict__ srcv,
                                              const int* __restrict__ tgt,
                                              int* __restrict__ cursor,
                                              int* __restrict__ csrf,
                                              int* flag) {
    __shared__ unsigned short smem[32 * XS];   // 24.5 KB: x tile; reused for h tile
    const int bid = blockIdx.x;
    const int tid = threadIdx.x;

    if (bid < NBLK_CONV) {
        // ---- conv role: frag-linear weight repacks (1 item per thread)
        int i = bid * 256 + tid;
        if (i < NW1) {
            int s = i;
            int jb = s / 768, rem = s - jb * 768;
            int kk = rem >> 6, lane = rem & 63;
            int ml = lane & 15, quad = lane >> 4;
            const float* p = W1 + (size_t)(jb * 16 + ml) * F_IN + kk * 32 + quad * 8;
            float4 u0 = *(const float4*)p;
            float4 u1 = *(const float4*)(p + 4);
            uint4 o;
            o.x = pk2bf(u0.x, u0.y); o.y = pk2bf(u0.z, u0.w);
            o.z = pk2bf(u1.x, u1.y); o.w = pk2bf(u1.z, u1.w);
            ((uint4*)w1b)[s] = o;
        } else if (i < NW1 + NW2) {
            int s = i - NW1;
            int jcol = s / 512, rem = s - jcol * 512;
            int kk = rem >> 6, lane = rem & 63;
            int ml = lane & 15, quad = lane >> 4;
            const float* p = W2 + (size_t)(jcol * 16 + ml) * H1 + kk * 32 + quad * 8;
            float4 u0 = *(const float4*)p;
            float4 u1 = *(const float4*)(p + 4);
            uint4 o;
            o.x = pk2bf(u0.x, u0.y); o.y = pk2bf(u0.z, u0.w);
            o.z = pk2bf(u1.x, u1.y); o.w = pk2bf(u1.z, u1.w);
            ((uint4*)w2b)[s] = o;
        } else {
            int j = i - NW1 - NW2;
            float4 v = ((const float4*)Wa1)[j];
            ushort4 o;
            o.x = f2bf(v.x); o.y = f2bf(v.y); o.z = f2bf(v.z); o.w = f2bf(v.w);
            ((ushort4*)wa1b)[j] = o;
        }
        asm volatile("s_waitcnt vmcnt(0)" ::: "memory");   // my stores at L2
        __syncthreads();                                   // whole block done
        if (tid == 0) {
            __builtin_amdgcn_fence(__ATOMIC_RELEASE, "agent");   // wb dirty L2
            __hip_atomic_fetch_add(flag, 1, __ATOMIC_RELAXED, __HIP_MEMORY_SCOPE_AGENT);
        }
        return;
    }

    if (bid >= NBLK_CONV + NBLK_FC) {
        // ---- fill role: fixed-stride CSR fill (cursor pre-zeroed by memset)
        int e0 = (bid - NBLK_CONV - NBLK_FC) * 1024 + tid;
        #pragma unroll
        for (int q = 0; q < 4; q++) {
            int e = e0 + q * 256;
            if (e < E_EDGES) {
                int t = tgt[e];
                int p = atomicAdd(&cursor[t], 1);
                if (p < DSTRIDE)
                    __builtin_nontemporal_store(srcv[e], &csrf[t * DSTRIDE + p]);
            }
        }
        return;
    }

    // ---- GEMM role
    int wave = tid >> 6;
    int lane = tid & 63;
    int m0 = (bid - NBLK_CONV) * 32;
    int rows = N_NODES - m0; if (rows > 32) rows = 32;   // 32 (or 16 for last block)
    int ml = lane & 15, quad = lane >> 4;
    {   // stage x tile: up to 32 rows x 384 fp32 -> bf16 LDS (overlaps conv wait)
        const float4* xsrc = (const float4*)(x + (size_t)m0 * F_IN);
        #pragma unroll
        for (int r = 0; r < 12; r++) {
            int idx = r * 256 + tid;
            int row = idx / 96, c4 = idx - row * 96;
            unsigned* sp = (unsigned*)(smem + row * XS + c4 * 4);
            if (row < rows) {
                float4 v = xsrc[idx];
                sp[0] = pk2bf(v.x, v.y);
                sp[1] = pk2bf(v.z, v.w);
            } else {
                sp[0] = 0u; sp[1] = 0u;
            }
        }
    }
    __syncthreads();
    if (tid == 0) {   // wait for all 72 conv blocks (one-shot, relaxed poll)
        int spins = 0;
        while (__hip_atomic_load(flag, __ATOMIC_RELAXED, __HIP_MEMORY_SCOPE_AGENT)
               < NBLK_CONV) {
            __builtin_amdgcn_s_sleep(2);
            if (++spins > (1 << 22)) break;   // failsafe: wrong results, no hang
        }
        __builtin_amdgcn_fence(__ATOMIC_ACQUIRE, "agent");   // inv stale L2 once
    }
    __syncthreads();
    f32x4 acc0[4] = {{0,0,0,0},{0,0,0,0},{0,0,0,0},{0,0,0,0}};
    f32x4 acc1[4] = {{0,0,0,0},{0,0,0,0},{0,0,0,0},{0,0,0,0}};
    {   // stage 1 K-loop: two 16-row A-frags share each B-frag (2x MFMA per B load)
        const unsigned short* ax0 = smem + ml * XS + quad * 8;
        const unsigned short* ax1 = smem + (16 + ml) * XS + quad * 8;
        const bf16x8* W1f = (const bf16x8*)w1b;
        for (int kk = 0; kk < F_IN / 32; kk++) {
            bf16x8 a0 = *(const bf16x8*)(ax0 + kk * 32);
            bf16x8 a1 = *(const bf16x8*)(ax1 + kk * 32);
            #pragma unroll
            for (int j = 0; j < 4; j++) {
                int jb = wave * 4 + j;
                bf16x8 b = W1f[(jb * 12 + kk) * 64 + lane];
                acc0[j] = __builtin_amdgcn_mfma_f32_16x16x32_bf16(a0, b, acc0[j], 0, 0, 0);
                acc1[j] = __builtin_amdgcn_mfma_f32_16x16x32_bf16(a1, b, acc1[j], 0, 0, 0);
            }
        }
    }
    __syncthreads();
    #pragma unroll
    for (int j = 0; j < 4; j++) {
        int col = wave * 64 + j * 16 + ml;
        float bb = b1[col];
        #pragma unroll
        for (int r = 0; r < 4; r++) {
            int lr = quad * 4 + r;
            float v0 = acc0[j][r] + bb;
            float v1 = acc1[j][r] + bb;
            smem[lr * S1 + col] = f2bf(v0 > 0.f ? v0 : 0.f);
            smem[(16 + lr) * S1 + col] = f2bf(v1 > 0.f ? v1 : 0.f);
        }
    }
    __syncthreads();
    {   // stage 2: z = h @ W2^T  (two row-halves share each B-frag)
        int c0 = wave * 32;
        const unsigned short* pA0 = smem + ml * S1 + quad * 8;
        const unsigned short* pA1 = smem + (16 + ml) * S1 + quad * 8;
        const bf16x8* W2f = (const bf16x8*)w2b;
        f32x4 za00 = {0,0,0,0}, za01 = {0,0,0,0}, za10 = {0,0,0,0}, za11 = {0,0,0,0};
        #pragma unroll
        for (int kk = 0; kk < H1 / 32; kk++) {
            bf16x8 a0 = *(const bf16x8*)(pA0 + kk * 32);
            bf16x8 a1 = *(const bf16x8*)(pA1 + kk * 32);
            bf16x8 b0 = W2f[((wave * 2 + 0) * 8 + kk) * 64 + lane];
            bf16x8 b1v = W2f[((wave * 2 + 1) * 8 + kk) * 64 + lane];
            za00 = __builtin_amdgcn_mfma_f32_16x16x32_bf16(a0, b0, za00, 0, 0, 0);
            za01 = __builtin_amdgcn_mfma_f32_16x16x32_bf16(a0, b1v, za01, 0, 0, 0);
            za10 = __builtin_amdgcn_mfma_f32_16x16x32_bf16(a1, b0, za10, 0, 0, 0);
            za11 = __builtin_amdgcn_mfma_f32_16x16x32_bf16(a1, b1v, za11, 0, 0, 0);
        }
        #pragma unroll
        for (int r = 0; r < 4; r++) {
            int row0 = m0 + quad * 4 + r;           // always < N_NODES
            z[(size_t)row0 * H2 + c0 + ml] = f2bf(za00[r]);
            z[(size_t)row0 * H2 + c0 + 16 + ml] = f2bf(za01[r]);
            int row1 = row0 + 16;
            if (row1 < N_NODES) {
                z[(size_t)row1 * H2 + c0 + ml] = f2bf(za10[r]);
                z[(size_t)row1 * H2 + c0 + 16 + ml] = f2bf(za11[r]);
            }
        }
    }
}

#define ACC8(v) { s0 += bflo(v.x); s1 += bfhi(v.x); s2 += bflo(v.y); s3 += bfhi(v.y); \
                  s4 += bflo(v.z); s5 += bfhi(v.z); s6 += bflo(v.w); s7 += bfhi(v.w); }

// ---------- agg pass 1 (round-3 body: 16 edges / 4 loads per runtime iteration)
__global__ __launch_bounds__(256) void k_agg1(const unsigned short* __restrict__ zin,
                                              unsigned short* __restrict__ zout,
                                              const int* __restrict__ cursor,
                                              const int* __restrict__ csrf) {
    int t = blockIdx.x * 4 + (threadIdx.x >> 6);
    int lane = threadIdx.x & 63;
    int l = lane & 15, quad = lane >> 4;
    int dg = cursor[t];
    if (dg > DSTRIDE) dg = DSTRIDE;
    const uint4* base = (const uint4*)zin;
    uint4 sv = make_uint4(0, 0, 0, 0);
    if (quad == 0) sv = base[(size_t)t * 16 + l];   // prefetch self row early
    float s0=0.f,s1=0.f,s2=0.f,s3=0.f,s4=0.f,s5=0.f,s6=0.f,s7=0.f;
    for (int e0 = 0; e0 < dg; e0 += 64) {
        int cnt = dg - e0; if (cnt > 64) cnt = 64;
        int c = (e0 + lane < dg) ? csrf[t * DSTRIDE + e0 + lane] : 0;
        for (int j = 0; j < cnt; j += 16) {
            int sA = __shfl(c, j + quad, 64);
            int sB = __shfl(c, j + 4 + quad, 64);
            int sC = __shfl(c, j + 8 + quad, 64);
            int sD = __shfl(c, j + 12 + quad, 64);
            uint4 vA = base[(size_t)sA * 16 + l];
            uint4 vB = base[(size_t)sB * 16 + l];
            uint4 vC = base[(size_t)sC * 16 + l];
            uint4 vD = base[(size_t)sD * 16 + l];
            if (j + quad < cnt)      ACC8(vA);
            if (j + 4 + quad < cnt)  ACC8(vB);
            if (j + 8 + quad < cnt)  ACC8(vC);
            if (j + 12 + quad < cnt) ACC8(vD);
        }
    }
    s0 += __shfl_xor(s0, 16, 64); s0 += __shfl_xor(s0, 32, 64);
    s1 += __shfl_xor(s1, 16, 64); s1 += __shfl_xor(s1, 32, 64);
    s2 += __shfl_xor(s2, 16, 64); s2 += __shfl_xor(s2, 32, 64);
    s3 += __shfl_xor(s3, 16, 64); s3 += __shfl_xor(s3, 32, 64);
    s4 += __shfl_xor(s4, 16, 64); s4 += __shfl_xor(s4, 32, 64);
    s5 += __shfl_xor(s5, 16, 64); s5 += __shfl_xor(s5, 32, 64);
    s6 += __shfl_xor(s6, 16, 64); s6 += __shfl_xor(s6, 32, 64);
    s7 += __shfl_xor(s7, 16, 64); s7 += __shfl_xor(s7, 32, 64);
    if (quad == 0) {
        float iv = 0.3f / (float)(dg + 1);
        uint4 o;
        o.x = pk2bf(0.7f * bflo(sv.x) + iv * s0, 0.7f * bfhi(sv.x) + iv * s1);
        o.y = pk2bf(0.7f * bflo(sv.y) + iv * s2, 0.7f * bfhi(sv.y) + iv * s3);
        o.z = pk2bf(0.7f * bflo(sv.z) + iv * s4, 0.7f * bfhi(sv.z) + iv * s5);
        o.w = pk2bf(0.7f * bflo(sv.w) + iv * s6, 0.7f * bfhi(sv.w) + iv * s7);
        ((uint4*)zout)[(size_t)t * 16 + l] = o;   // stays in L2: pass 2's gather table
    }
}

// ---------- agg pass 2 + epilogue (round-3 body, bf16 wa1b att head, + ba2)
__global__ __launch_bounds__(256) void k_agg2fin(const unsigned short* __restrict__ zin,
                                                 const int* __restrict__ cursor,
                                                 const int* __restrict__ csrf,
                                                 const float* __restrict__ b2,
                                                 const unsigned short* __restrict__ wa1b,
                                                 const float* __restrict__ ba1,
                                                 const float* __restrict__ Wa2,
                                                 const float* __restrict__ ba2,
                                                 float* __restrict__ out,
                                                 float* __restrict__ att) {
    __shared__ float sout[4][128];
    int nl = threadIdx.x >> 6;
    int t = blockIdx.x * 4 + nl;
    int lane = threadIdx.x & 63;
    int l = lane & 15, quad = lane >> 4;
    int dg = cursor[t];
    if (dg > DSTRIDE) dg = DSTRIDE;
    const uint4* base = (const uint4*)zin;
    uint4 sv = base[(size_t)t * 16 + l];   // prefetch self row (all quads need it)
    float s0=0.f,s1=0.f,s2=0.f,s3=0.f,s4=0.f,s5=0.f,s6=0.f,s7=0.f;
    for (int e0 = 0; e0 < dg; e0 += 64) {
        int cnt = dg - e0; if (cnt > 64) cnt = 64;
        int c = (e0 + lane < dg) ? csrf[t * DSTRIDE + e0 + lane] : 0;
        for (int j = 0; j < cnt; j += 16) {
            int sA = __shfl(c, j + quad, 64);
            int sB = __shfl(c, j + 4 + quad, 64);
            int sC = __shfl(c, j + 8 + quad, 64);
            int sD = __shfl(c, j + 12 + quad, 64);
            uint4 vA = base[(size_t)sA * 16 + l];
            uint4 vB = base[(size_t)sB * 16 + l];
            uint4 vC = base[(size_t)sC * 16 + l];
            uint4 vD = base[(size_t)sD * 16 + l];
            if (j + quad < cnt)      ACC8(vA);
            if (j + 4 + quad < cnt)  ACC8(vB);
            if (j + 8 + quad < cnt)  ACC8(vC);
            if (j + 12 + quad < cnt) ACC8(vD);
        }
    }
    s0 += __shfl_xor(s0, 16, 64); s0 += __shfl_xor(s0, 32, 64);
    s1 += __shfl_xor(s1, 16, 64); s1 += __shfl_xor(s1, 32, 64);
    s2 += __shfl_xor(s2, 16, 64); s2 += __shfl_xor(s2, 32, 64);
    s3 += __shfl_xor(s3, 16, 64); s3 += __shfl_xor(s3, 32, 64);
    s4 += __shfl_xor(s4, 16, 64); s4 += __shfl_xor(s4, 32, 64);
    s5 += __shfl_xor(s5, 16, 64); s5 += __shfl_xor(s5, 32, 64);
    s6 += __shfl_xor(s6, 16, 64); s6 += __shfl_xor(s6, 32, 64);
    s7 += __shfl_xor(s7, 16, 64); s7 += __shfl_xor(s7, 32, 64);
    // epilogue: all quads hold full sums for cols l*8..l*8+7
    float iv = 0.3f / (float)(dg + 1);
    const float4* bp = (const float4*)(b2 + l * 8);
    float4 bA = bp[0], bB = bp[1];
    float f0 = 0.7f * bflo(sv.x) + iv * s0 + bA.x;  f0 = f0 > 0.f ? f0 : 0.f;
    float f1 = 0.7f * bfhi(sv.x) + iv * s1 + bA.y;  f1 = f1 > 0.f ? f1 : 0.f;
    float f2 = 0.7f * bflo(sv.y) + iv * s2 + bA.z;  f2 = f2 > 0.f ? f2 : 0.f;
    float f3 = 0.7f * bfhi(sv.y) + iv * s3 + bA.w;  f3 = f3 > 0.f ? f3 : 0.f;
    float f4 = 0.7f * bflo(sv.z) + iv * s4 + bB.x;  f4 = f4 > 0.f ? f4 : 0.f;
    float f5 = 0.7f * bfhi(sv.z) + iv * s5 + bB.y;  f5 = f5 > 0.f ? f5 : 0.f;
    float f6 = 0.7f * bflo(sv.w) + iv * s6 + bB.z;  f6 = f6 > 0.f ? f6 : 0.f;
    float f7 = 0.7f * bfhi(sv.w) + iv * s7 + bB.w;  f7 = f7 > 0.f ? f7 : 0.f;
    // quads split the stores: q0/q1 -> global out, q2/q3 -> LDS for att
    float* orow = out + (size_t)t * H2 + l * 8;
    if (quad == 0) *(float4*)orow = make_float4(f0, f1, f2, f3);
    else if (quad == 1) *(float4*)(orow + 4) = make_float4(f4, f5, f6, f7);
    else if (quad == 2) *(float4*)(&sout[nl][l * 8]) = make_float4(f0, f1, f2, f3);
    else *(float4*)(&sout[nl][l * 8 + 4]) = make_float4(f4, f5, f6, f7);
    // att: lane u computes hidden unit u: dot(out_row, Wa1[u]) over K=128
    float acc = ba1[lane];
    const bf16x8* wrow = (const bf16x8*)(wa1b + (size_t)lane * H2);
    const float* srow = sout[nl];
    #pragma unroll
    for (int k8 = 0; k8 < 16; k8++) {
        bf16x8 w = wrow[k8];
        #pragma unroll
        for (int u = 0; u < 8; u++)
            acc += bf2f(w[u]) * srow[k8 * 8 + u];   // loop-uniform LDS index -> broadcast
    }
    float g = (acc > 0.f ? acc : 0.f) * Wa2[lane];
    #pragma unroll
    for (int d = 1; d < 64; d <<= 1) g += __shfl_xor(g, d, 64);
    if (lane == 0) att[t] = 1.f / (1.f + expf(-(g + ba2[0])));
}

extern "C" void kernel_launch(void* const* d_in, const int* in_sizes, int n_in,
                              void* d_out, int out_size, void* d_ws, size_t ws_size,
                              hipStream_t stream) {
    const float* x   = (const float*)d_in[0];
    const int*   ei  = (const int*)d_in[1];
    const float* W1  = (const float*)d_in[2];
    const float* b1  = (const float*)d_in[3];
    const float* W2  = (const float*)d_in[4];
    const float* b2  = (const float*)d_in[5];
    const float* Wa1 = (const float*)d_in[6];
    const float* ba1 = (const float*)d_in[7];
    const float* Wa2 = (const float*)d_in[8];
    const float* ba2 = (const float*)d_in[9];
    const int* srcv = ei;
    const int* tgt  = ei + E_EDGES;

    float* out_mat = (float*)d_out;                 // N x 128
    float* att     = out_mat + N_NODES * H2;        // N x 1

    // workspace layout
    unsigned short* w1b  = (unsigned short*)d_ws;                // H1*F_IN (frag-linear)
    unsigned short* w2b  = w1b + (size_t)H1 * F_IN;              // H2*H1   (frag-linear)
    unsigned short* wa1b = w2b + (size_t)H2 * H1;                // ATT1*H2 (row-major)
    unsigned short* z0   = wa1b + (size_t)ATT1 * H2;             // N*128 bf16
    unsigned short* z1   = z0 + (size_t)N_NODES * H2;            // N*128 bf16
    int* cursor = (int*)(z1 + (size_t)N_NODES * H2);             // N ints
    int* flag   = cursor + N_NODES;                              // 1 int (conv done-count)
    int* csrf   = flag + 16;                                     // N*DSTRIDE ints

    // zero cursors + flag in one small memset (40 KB + 64 B)
    hipMemsetAsync(cursor, 0, (N_NODES + 16) * sizeof(int), stream);

    // merged: repack (72) | fc1+proj GEMM (313) | CSR fill (313) = 1010 blocks
    k_main<<<NBLK_CONV + NBLK_FC + NBLK_FIL, 256, 0, stream>>>(
        x, W1, b1, W2, Wa1, w1b, w2b, wa1b, z0, srcv, tgt, cursor, csrf, flag);

    // agg pass 1 (z0 -> z1)
    k_agg1<<<N_NODES / 4, 256, 0, stream>>>(z0, z1, cursor, csrf);

    // agg pass 2 + bias/relu -> out, att head -> att
    k_agg2fin<<<N_NODES / 4, 256, 0, stream>>>(z1, cursor, csrf, b2,
                                               wa1b, ba1, Wa2, ba2, out_mat, att);
}

// Round 9
// 143.505 us; speedup vs baseline: 5.2796x; 1.0427x over previous
//
#include <hip/hip_runtime.h>
#include <hip/hip_bf16.h>
#include <math.h>

#define N_NODES 10000
#define E_EDGES 320000
#define F_IN    384
#define H1      256
#define H2      128
#define ATT1    64
#define DSTRIDE 128   // fixed CSR stride; P(deg>=128) ~ 4e-32 for Binomial(320k, 1e-4)

typedef __attribute__((ext_vector_type(8))) short bf16x8;
typedef __attribute__((ext_vector_type(4))) float f32x4;

static __device__ inline unsigned short f2bf(float f) {
    unsigned u = __float_as_uint(f);
    unsigned r = (u + 0x7fffu + ((u >> 16) & 1u)) >> 16;   // RNE
    return (unsigned short)r;
}

static __device__ inline unsigned pk2bf(float a, float b) {
    __hip_bfloat162 h2 = __float22bfloat162_rn(make_float2(a, b));
    return *reinterpret_cast<unsigned*>(&h2);   // v_cvt_pk_bf16_f32
}

static __device__ inline float bflo(unsigned v) { return __uint_as_float(v << 16); }
static __device__ inline float bfhi(unsigned v) { return __uint_as_float(v & 0xffff0000u); }
static __device__ inline float bf2f(short s) {
    return __uint_as_float(((unsigned)(unsigned short)s) << 16);
}

// ---------- k_conv: frag-linear weight repacks + Wa1 convert + cursor zeroing
#define NW1 (H1 * F_IN / 8)   // 12288 uint4 slots
#define NW2 (H2 * H1 / 8)     // 4096
#define NWA (ATT1 * H2 / 4)   // 2048 float4 -> ushort4
#define NCZ (N_NODES / 4)     // 2500 int4 zeroes
__global__ void k_conv(const float* __restrict__ W1, const float* __restrict__ W2,
                       const float* __restrict__ Wa1,
                       unsigned short* __restrict__ w1b, unsigned short* __restrict__ w2b,
                       unsigned short* __restrict__ wa1b,
                       int* __restrict__ cursor) {
    int i = blockIdx.x * blockDim.x + threadIdx.x;
    if (i < NW1) {
        int s = i;
        int jb = s / 768, rem = s - jb * 768;
        int kk = rem >> 6, lane = rem & 63;
        int ml = lane & 15, quad = lane >> 4;
        const float* p = W1 + (size_t)(jb * 16 + ml) * F_IN + kk * 32 + quad * 8;
        float4 u0 = *(const float4*)p;
        float4 u1 = *(const float4*)(p + 4);
        uint4 o;
        o.x = pk2bf(u0.x, u0.y); o.y = pk2bf(u0.z, u0.w);
        o.z = pk2bf(u1.x, u1.y); o.w = pk2bf(u1.z, u1.w);
        ((uint4*)w1b)[s] = o;
    } else if (i < NW1 + NW2) {
        int s = i - NW1;
        int jcol = s / 512, rem = s - jcol * 512;
        int kk = rem >> 6, lane = rem & 63;
        int ml = lane & 15, quad = lane >> 4;
        const float* p = W2 + (size_t)(jcol * 16 + ml) * H1 + kk * 32 + quad * 8;
        float4 u0 = *(const float4*)p;
        float4 u1 = *(const float4*)(p + 4);
        uint4 o;
        o.x = pk2bf(u0.x, u0.y); o.y = pk2bf(u0.z, u0.w);
        o.z = pk2bf(u1.x, u1.y); o.w = pk2bf(u1.z, u1.w);
        ((uint4*)w2b)[s] = o;
    } else if (i < NW1 + NW2 + NWA) {
        int j = i - NW1 - NW2;
        float4 v = ((const float4*)Wa1)[j];
        ushort4 o;
        o.x = f2bf(v.x); o.y = f2bf(v.y); o.z = f2bf(v.z); o.w = f2bf(v.w);
        ((ushort4*)wa1b)[j] = o;
    } else {
        int j = i - NW1 - NW2 - NWA;
        if (j < NCZ) ((int4*)cursor)[j] = make_int4(0, 0, 0, 0);
    }
}

// ---------- fused: fc1+proj GEMM (32-row blocks) + fixed-stride CSR fill
#define NBLK_FC  313                             // 312 full 32-row blocks + 1 ragged 16-row
#define NBLK_FIL ((E_EDGES + 1023) / 1024)       // 313 (4 edges/thread)
#define XS 392   // LDS row stride (ushorts) for the 32x384 x tile
#define S1 264   // LDS row stride (ushorts) for the 32x256 h tile
__global__ __launch_bounds__(256) void k_fc12fill(const float* __restrict__ x,
                                                  const unsigned short* __restrict__ w1b,
                                                  const float* __restrict__ b1,
                                                  const unsigned short* __restrict__ w2b,
                                                  unsigned short* __restrict__ z,
                                                  const int* __restrict__ srcv,
                                                  const int* __restrict__ tgt,
                                                  int* __restrict__ cursor,
                                                  unsigned short* __restrict__ csrf) {
    __shared__ unsigned short smem[32 * XS];   // 24.5 KB: x tile; reused for h tile
    if (blockIdx.x >= NBLK_FC) {
        int e0 = (blockIdx.x - NBLK_FC) * 1024 + threadIdx.x;
        #pragma unroll
        for (int q = 0; q < 4; q++) {
            int e = e0 + q * 256;
            if (e < E_EDGES) {
                int t = tgt[e];
                int p = atomicAdd(&cursor[t], 1);
                if (p < DSTRIDE)
                    __builtin_nontemporal_store((unsigned short)srcv[e],
                                                &csrf[t * DSTRIDE + p]);
            }
        }
        return;
    }
    int wave = threadIdx.x >> 6;
    int lane = threadIdx.x & 63;
    int m0 = blockIdx.x * 32;
    int rows = N_NODES - m0; if (rows > 32) rows = 32;   // 32 (or 16 for last block)
    int ml = lane & 15, quad = lane >> 4;
    {   // stage x tile: up to 32 rows x 384 fp32 -> bf16 LDS, coalesced
        const float4* xsrc = (const float4*)(x + (size_t)m0 * F_IN);
        #pragma unroll
        for (int r = 0; r < 12; r++) {
            int idx = r * 256 + threadIdx.x;
            int row = idx / 96, c4 = idx - row * 96;
            unsigned* sp = (unsigned*)(smem + row * XS + c4 * 4);
            if (row < rows) {
                float4 v = xsrc[idx];
                sp[0] = pk2bf(v.x, v.y);
                sp[1] = pk2bf(v.z, v.w);
            } else {
                sp[0] = 0u; sp[1] = 0u;
            }
        }
    }
    __syncthreads();
    f32x4 acc0[4] = {{0,0,0,0},{0,0,0,0},{0,0,0,0},{0,0,0,0}};
    f32x4 acc1[4] = {{0,0,0,0},{0,0,0,0},{0,0,0,0},{0,0,0,0}};
    {   // stage 1 K-loop: two 16-row A-frags share each B-frag (2x MFMA per B load)
        const unsigned short* ax0 = smem + ml * XS + quad * 8;
        const unsigned short* ax1 = smem + (16 + ml) * XS + quad * 8;
        const bf16x8* W1f = (const bf16x8*)w1b;
        for (int kk = 0; kk < F_IN / 32; kk++) {
            bf16x8 a0 = *(const bf16x8*)(ax0 + kk * 32);
            bf16x8 a1 = *(const bf16x8*)(ax1 + kk * 32);
            #pragma unroll
            for (int j = 0; j < 4; j++) {
                int jb = wave * 4 + j;
                bf16x8 b = W1f[(jb * 12 + kk) * 64 + lane];
                acc0[j] = __builtin_amdgcn_mfma_f32_16x16x32_bf16(a0, b, acc0[j], 0, 0, 0);
                acc1[j] = __builtin_amdgcn_mfma_f32_16x16x32_bf16(a1, b, acc1[j], 0, 0, 0);
            }
        }
    }
    __syncthreads();
    #pragma unroll
    for (int j = 0; j < 4; j++) {
        int col = wave * 64 + j * 16 + ml;
        float bb = b1[col];
        #pragma unroll
        for (int r = 0; r < 4; r++) {
            int lr = quad * 4 + r;
            float v0 = acc0[j][r] + bb;
            float v1 = acc1[j][r] + bb;
            smem[lr * S1 + col] = f2bf(v0 > 0.f ? v0 : 0.f);
            smem[(16 + lr) * S1 + col] = f2bf(v1 > 0.f ? v1 : 0.f);
        }
    }
    __syncthreads();
    {   // stage 2: z = h @ W2^T  (two row-halves share each B-frag)
        int c0 = wave * 32;
        const unsigned short* pA0 = smem + ml * S1 + quad * 8;
        const unsigned short* pA1 = smem + (16 + ml) * S1 + quad * 8;
        const bf16x8* W2f = (const bf16x8*)w2b;
        f32x4 za00 = {0,0,0,0}, za01 = {0,0,0,0}, za10 = {0,0,0,0}, za11 = {0,0,0,0};
        #pragma unroll
        for (int kk = 0; kk < H1 / 32; kk++) {
            bf16x8 a0 = *(const bf16x8*)(pA0 + kk * 32);
            bf16x8 a1 = *(const bf16x8*)(pA1 + kk * 32);
            bf16x8 b0 = W2f[((wave * 2 + 0) * 8 + kk) * 64 + lane];
            bf16x8 b1v = W2f[((wave * 2 + 1) * 8 + kk) * 64 + lane];
            za00 = __builtin_amdgcn_mfma_f32_16x16x32_bf16(a0, b0, za00, 0, 0, 0);
            za01 = __builtin_amdgcn_mfma_f32_16x16x32_bf16(a0, b1v, za01, 0, 0, 0);
            za10 = __builtin_amdgcn_mfma_f32_16x16x32_bf16(a1, b0, za10, 0, 0, 0);
            za11 = __builtin_amdgcn_mfma_f32_16x16x32_bf16(a1, b1v, za11, 0, 0, 0);
        }
        #pragma unroll
        for (int r = 0; r < 4; r++) {
            int row0 = m0 + quad * 4 + r;           // always < N_NODES
            z[(size_t)row0 * H2 + c0 + ml] = f2bf(za00[r]);
            z[(size_t)row0 * H2 + c0 + 16 + ml] = f2bf(za01[r]);
            int row1 = row0 + 16;
            if (row1 < N_NODES) {
                z[(size_t)row1 * H2 + c0 + ml] = f2bf(za10[r]);
                z[(size_t)row1 * H2 + c0 + 16 + ml] = f2bf(za11[r]);
            }
        }
    }
}

#define ACC8(v) { s0 += bflo(v.x); s1 += bfhi(v.x); s2 += bflo(v.y); s3 += bfhi(v.y); \
                  s4 += bflo(v.z); s5 += bfhi(v.z); s6 += bflo(v.w); s7 += bfhi(v.w); }

// 2-deep software-pipelined gather: group g+1's shfl+loads issue BEFORE group g's
// consume, so the compiler waits with vmcnt(4) instead of vmcnt(0) -> ~2 serial
// latency rounds per node instead of ~4. Groups issue conditionally on the
// wave-uniform dg (no R7-style wasted loads). Loads unconditional within a group
// (zero-padded c -> padding lanes hit the hot row-0 lines); adds predicated.
#define ISSUE(R, g) { \
    int sA = __shfl(c, (g) * 16 + quad, 64); \
    int sB = __shfl(c, (g) * 16 + 4 + quad, 64); \
    int sC = __shfl(c, (g) * 16 + 8 + quad, 64); \
    int sD = __shfl(c, (g) * 16 + 12 + quad, 64); \
    vA##R = base[(size_t)sA * 16 + l]; \
    vB##R = base[(size_t)sB * 16 + l]; \
    vC##R = base[(size_t)sC * 16 + l]; \
    vD##R = base[(size_t)sD * 16 + l]; }
#define CONSUME(R, g) { \
    if ((g) * 16 + quad < cnt)      ACC8(vA##R); \
    if ((g) * 16 + 4 + quad < cnt)  ACC8(vB##R); \
    if ((g) * 16 + 8 + quad < cnt)  ACC8(vC##R); \
    if ((g) * 16 + 12 + quad < cnt) ACC8(vD##R); }

// gathers for one node (t, dg wave-uniform); declares/uses s0..s7, base, l, quad, lane
#define GATHER_PIPE()                                                         \
    {                                                                         \
        int cnt = dg > 64 ? 64 : dg;                                          \
        int c = (lane < cnt) ? (int)csrf[t * DSTRIDE + lane] : 0;             \
        uint4 vA0, vB0, vC0, vD0, vA1, vB1, vC1, vD1;                         \
        ISSUE(0, 0);                                                          \
        if (cnt > 16) ISSUE(1, 1);                                            \
        CONSUME(0, 0);                                                        \
        if (cnt > 16) {                                                       \
            if (cnt > 32) ISSUE(0, 2);                                        \
            CONSUME(1, 1);                                                    \
            if (cnt > 32) {                                                   \
                if (cnt > 48) ISSUE(1, 3);                                    \
                CONSUME(0, 2);                                                \
                if (cnt > 48) CONSUME(1, 3);                                  \
            }                                                                 \
        }                                                                     \
        if (dg > 64) {   /* rare tail (P ~ 1e-7 per node): plain loop */      \
            for (int e0 = 64; e0 < dg; e0 += 64) {                            \
                cnt = dg - e0; if (cnt > 64) cnt = 64;                        \
                c = (e0 + lane < dg) ? (int)csrf[t * DSTRIDE + e0 + lane] : 0;\
                for (int j = 0; j < cnt; j += 16) {                           \
                    ISSUE(0, 0);   /* g=0 with c offset: shfl idx j+... */    \
                    CONSUME(0, 0);                                            \
                }                                                             \
            }                                                                 \
        }                                                                     \
    }

#define QUADRED()                                                             \
    s0 += __shfl_xor(s0, 16, 64); s0 += __shfl_xor(s0, 32, 64);               \
    s1 += __shfl_xor(s1, 16, 64); s1 += __shfl_xor(s1, 32, 64);               \
    s2 += __shfl_xor(s2, 16, 64); s2 += __shfl_xor(s2, 32, 64);               \
    s3 += __shfl_xor(s3, 16, 64); s3 += __shfl_xor(s3, 32, 64);               \
    s4 += __shfl_xor(s4, 16, 64); s4 += __shfl_xor(s4, 32, 64);               \
    s5 += __shfl_xor(s5, 16, 64); s5 += __shfl_xor(s5, 32, 64);               \
    s6 += __shfl_xor(s6, 16, 64); s6 += __shfl_xor(s6, 32, 64);               \
    s7 += __shfl_xor(s7, 16, 64); s7 += __shfl_xor(s7, 32, 64);

// NOTE on the dg>64 tail: ISSUE(0,0)/CONSUME(0,0) inside the j-loop use shfl
// index (0*16+..), but the edges processed must be j+.. — fix by shifting c:
// we rotate c by re-loading per chunk and using __shfl(c, j + ..) explicitly.
// To keep the macro simple and the tail correct, the tail re-expands manually:
#undef GATHER_PIPE
#define GATHER_PIPE()                                                         \
    {                                                                         \
        int cnt = dg > 64 ? 64 : dg;                                          \
        int c = (lane < cnt) ? (int)csrf[t * DSTRIDE + lane] : 0;             \
        uint4 vA0, vB0, vC0, vD0, vA1, vB1, vC1, vD1;                         \
        ISSUE(0, 0);                                                          \
        if (cnt > 16) ISSUE(1, 1);                                            \
        CONSUME(0, 0);                                                        \
        if (cnt > 16) {                                                       \
            if (cnt > 32) ISSUE(0, 2);                                        \
            CONSUME(1, 1);                                                    \
            if (cnt > 32) {                                                   \
                if (cnt > 48) ISSUE(1, 3);                                    \
                CONSUME(0, 2);                                                \
                if (cnt > 48) CONSUME(1, 3);                                  \
            }                                                                 \
        }                                                                     \
        for (int e0 = 64; e0 < dg; e0 += 64) {   /* rare tail, P~1e-7 */      \
            cnt = dg - e0; if (cnt > 64) cnt = 64;                            \
            c = (e0 + lane < dg) ? (int)csrf[t * DSTRIDE + e0 + lane] : 0;    \
            for (int j = 0; j < cnt; j += 16) {                               \
                int sA = __shfl(c, j + quad, 64);                             \
                int sB = __shfl(c, j + 4 + quad, 64);                         \
                int sC = __shfl(c, j + 8 + quad, 64);                         \
                int sD = __shfl(c, j + 12 + quad, 64);                        \
                uint4 vA = base[(size_t)sA * 16 + l];                         \
                uint4 vB = base[(size_t)sB * 16 + l];                         \
                uint4 vC = base[(size_t)sC * 16 + l];                         \
                uint4 vD = base[(size_t)sD * 16 + l];                         \
                if (j + quad < cnt)      ACC8(vA);                            \
                if (j + 4 + quad < cnt)  ACC8(vB);                            \
                if (j + 8 + quad < cnt)  ACC8(vC);                            \
                if (j + 12 + quad < cnt) ACC8(vD);                            \
            }                                                                 \
        }                                                                     \
    }

// ---------- agg pass 1 (z0 -> z1)
__global__ __launch_bounds__(256) void k_agg1(const unsigned short* __restrict__ zin,
                                              unsigned short* __restrict__ zout,
                                              const int* __restrict__ cursor,
                                              const unsigned short* __restrict__ csrf) {
    int t = blockIdx.x * 4 + (threadIdx.x >> 6);
    int lane = threadIdx.x & 63;
    int l = lane & 15, quad = lane >> 4;
    int dg = cursor[t];
    if (dg > DSTRIDE) dg = DSTRIDE;
    const uint4* base = (const uint4*)zin;
    uint4 sv = make_uint4(0, 0, 0, 0);
    if (quad == 0) sv = base[(size_t)t * 16 + l];   // prefetch self row early
    float s0=0.f,s1=0.f,s2=0.f,s3=0.f,s4=0.f,s5=0.f,s6=0.f,s7=0.f;
    GATHER_PIPE();
    QUADRED();
    if (quad == 0) {
        float iv = 0.3f / (float)(dg + 1);
        uint4 o;
        o.x = pk2bf(0.7f * bflo(sv.x) + iv * s0, 0.7f * bfhi(sv.x) + iv * s1);
        o.y = pk2bf(0.7f * bflo(sv.y) + iv * s2, 0.7f * bfhi(sv.y) + iv * s3);
        o.z = pk2bf(0.7f * bflo(sv.z) + iv * s4, 0.7f * bfhi(sv.z) + iv * s5);
        o.w = pk2bf(0.7f * bflo(sv.w) + iv * s6, 0.7f * bfhi(sv.w) + iv * s7);
        ((uint4*)zout)[(size_t)t * 16 + l] = o;   // stays in L2: pass 2's gather table
    }
}

// ---------- agg pass 2 + epilogue, out fp32 + att head (bf16 wa1b, float4 LDS reads)
__global__ __launch_bounds__(256) void k_agg2fin(const unsigned short* __restrict__ zin,
                                                 const int* __restrict__ cursor,
                                                 const unsigned short* __restrict__ csrf,
                                                 const float* __restrict__ b2,
                                                 const unsigned short* __restrict__ wa1b,
                                                 const float* __restrict__ ba1,
                                                 const float* __restrict__ Wa2,
                                                 const float* __restrict__ ba2,
                                                 float* __restrict__ out,
                                                 float* __restrict__ att) {
    __shared__ float sout[4][128];
    int nl = threadIdx.x >> 6;
    int t = blockIdx.x * 4 + nl;
    int lane = threadIdx.x & 63;
    int l = lane & 15, quad = lane >> 4;
    int dg = cursor[t];
    if (dg > DSTRIDE) dg = DSTRIDE;
    const uint4* base = (const uint4*)zin;
    uint4 sv = base[(size_t)t * 16 + l];   // prefetch self row (all quads need it)
    float s0=0.f,s1=0.f,s2=0.f,s3=0.f,s4=0.f,s5=0.f,s6=0.f,s7=0.f;
    GATHER_PIPE();
    QUADRED();
    // epilogue: all quads hold full sums for cols l*8..l*8+7
    float iv = 0.3f / (float)(dg + 1);
    const float4* bp = (const float4*)(b2 + l * 8);
    float4 bA = bp[0], bB = bp[1];
    float f0 = 0.7f * bflo(sv.x) + iv * s0 + bA.x;  f0 = f0 > 0.f ? f0 : 0.f;
    float f1 = 0.7f * bfhi(sv.x) + iv * s1 + bA.y;  f1 = f1 > 0.f ? f1 : 0.f;
    float f2 = 0.7f * bflo(sv.y) + iv * s2 + bA.z;  f2 = f2 > 0.f ? f2 : 0.f;
    float f3 = 0.7f * bfhi(sv.y) + iv * s3 + bA.w;  f3 = f3 > 0.f ? f3 : 0.f;
    float f4 = 0.7f * bflo(sv.z) + iv * s4 + bB.x;  f4 = f4 > 0.f ? f4 : 0.f;
    float f5 = 0.7f * bfhi(sv.z) + iv * s5 + bB.y;  f5 = f5 > 0.f ? f5 : 0.f;
    float f6 = 0.7f * bflo(sv.w) + iv * s6 + bB.z;  f6 = f6 > 0.f ? f6 : 0.f;
    float f7 = 0.7f * bfhi(sv.w) + iv * s7 + bB.w;  f7 = f7 > 0.f ? f7 : 0.f;
    // quads split the stores: q0/q1 -> global out, q2/q3 -> LDS for att
    float* orow = out + (size_t)t * H2 + l * 8;
    if (quad == 0) *(float4*)orow = make_float4(f0, f1, f2, f3);
    else if (quad == 1) *(float4*)(orow + 4) = make_float4(f4, f5, f6, f7);
    else if (quad == 2) *(float4*)(&sout[nl][l * 8]) = make_float4(f0, f1, f2, f3);
    else *(float4*)(&sout[nl][l * 8 + 4]) = make_float4(f4, f5, f6, f7);
    // att: lane u computes hidden unit u: dot(out_row, Wa1[u]) over K=128
    float acc = ba1[lane];
    const bf16x8* wrow = (const bf16x8*)(wa1b + (size_t)lane * H2);
    const float4* s4v = (const float4*)sout[nl];
    #pragma unroll
    for (int k8 = 0; k8 < 16; k8++) {
        bf16x8 w = wrow[k8];
        float4 p0 = s4v[k8 * 2];       // ds_read_b128 broadcast (uniform addr)
        float4 p1 = s4v[k8 * 2 + 1];
        acc += bf2f(w[0]) * p0.x + bf2f(w[1]) * p0.y
             + bf2f(w[2]) * p0.z + bf2f(w[3]) * p0.w
             + bf2f(w[4]) * p1.x + bf2f(w[5]) * p1.y
             + bf2f(w[6]) * p1.z + bf2f(w[7]) * p1.w;
    }
    float g = (acc > 0.f ? acc : 0.f) * Wa2[lane];
    #pragma unroll
    for (int d = 1; d < 64; d <<= 1) g += __shfl_xor(g, d, 64);
    if (lane == 0) att[t] = 1.f / (1.f + expf(-(g + ba2[0])));
}

extern "C" void kernel_launch(void* const* d_in, const int* in_sizes, int n_in,
                              void* d_out, int out_size, void* d_ws, size_t ws_size,
                              hipStream_t stream) {
    const float* x   = (const float*)d_in[0];
    const int*   ei  = (const int*)d_in[1];
    const float* W1  = (const float*)d_in[2];
    const float* b1  = (const float*)d_in[3];
    const float* W2  = (const float*)d_in[4];
    const float* b2  = (const float*)d_in[5];
    const float* Wa1 = (const float*)d_in[6];
    const float* ba1 = (const float*)d_in[7];
    const float* Wa2 = (const float*)d_in[8];
    const float* ba2 = (const float*)d_in[9];
    const int* srcv = ei;
    const int* tgt  = ei + E_EDGES;

    float* out_mat = (float*)d_out;                 // N x 128
    float* att     = out_mat + N_NODES * H2;        // N x 1

    // workspace layout
    unsigned short* w1b  = (unsigned short*)d_ws;                // H1*F_IN (frag-linear)
    unsigned short* w2b  = w1b + (size_t)H1 * F_IN;              // H2*H1   (frag-linear)
    unsigned short* wa1b = w2b + (size_t)H2 * H1;                // ATT1*H2 (row-major)
    unsigned short* z0   = wa1b + (size_t)ATT1 * H2;             // N*128 bf16
    unsigned short* z1   = z0 + (size_t)N_NODES * H2;            // N*128 bf16
    int* cursor = (int*)(z1 + (size_t)N_NODES * H2);             // N ints
    unsigned short* csrf = (unsigned short*)(cursor + N_NODES);  // N*DSTRIDE ushort

    // frag-linear weight repacks + Wa1 convert + cursor zeroing (one launch)
    {
        int total = NW1 + NW2 + NWA + NCZ;   // 20932
        k_conv<<<(total + 255) / 256, 256, 0, stream>>>(W1, W2, Wa1, w1b, w2b, wa1b, cursor);
    }

    // fused fc1+proj GEMM (313 blocks, M=32) + fixed-stride CSR fill (313 blocks)
    k_fc12fill<<<NBLK_FC + NBLK_FIL, 256, 0, stream>>>(x, w1b, b1, w2b, z0,
                                                       srcv, tgt, cursor, csrf);

    // agg pass 1 (z0 -> z1)
    k_agg1<<<N_NODES / 4, 256, 0, stream>>>(z0, z1, cursor, csrf);

    // agg pass 2 + bias/relu -> out, att head -> att
    k_agg2fin<<<N_NODES / 4, 256, 0, stream>>>(z1, cursor, csrf, b2,
                                               wa1b, ba1, Wa2, ba2, out_mat, att);
}